// Round 13
// baseline (74.137 us; speedup 1.0000x reference)
//
#include <hip/hip_runtime.h>
#include <hip/hip_bf16.h>
#include <math.h>

#define D 768
#define NCLS 96
#define M 8192            // 32*256 tokens
#define NROWS (M + NCLS)  // 8288 grouped rows
#define EPS 1e-5f

// gram geometry (proven round-3)
#define KB 384
#define SEGR 48           // KB/8 16B segments per row-chunk
#define MAXR 160          // max rows per class (dict + tokens)
#define DYN_B (MAXR * KB * 2)   // 122880 B dynamic LDS

typedef __attribute__((ext_vector_type(8))) short bf16x8;
typedef __attribute__((ext_vector_type(4))) float f32x4;

// tick[0] = neg-done count, tick[1] = cd-done count, tick[2] = gram-done count

// ---------------- K2: counts/gofs/perm + dict copy (round-3 proven) -------------
__global__ __launch_bounds__(256) void k2_lists(const int* __restrict__ labels,
        const float* __restrict__ cdic, int* __restrict__ perm,
        int* __restrict__ counts, int* __restrict__ gofs,
        __hip_bfloat16* __restrict__ xgb, unsigned int* __restrict__ tick) {
    int c = blockIdx.x;
    int tid = threadIdx.x, wave = tid >> 6, lane = tid & 63;
    __shared__ int labs[M];
    __shared__ int ccnt[128];
    __shared__ int cbase[128];
    __shared__ int ltred[4];
    __shared__ int gsh;
    if (c == 0 && tid < 3) tick[tid] = 0u;    // reset all tickets each call
    for (int t = tid; t < M / 4; t += 256)
        ((int4*)labs)[t] = ((const int4*)labels)[t];
    __syncthreads();
    int lt0 = 0;
    for (int ch = wave; ch < 128; ch += 4) {
        int lab = labs[ch * 64 + lane];
        unsigned long long meq = __ballot(lab == c);
        unsigned long long mlt = __ballot(lab < c);
        if (lane == 0) { ccnt[ch] = __popcll(meq); lt0 += __popcll(mlt); }
    }
    if (lane == 0) ltred[wave] = lt0;
    __syncthreads();
    if (wave == 0) {
        int v0 = ccnt[lane], v1 = ccnt[64 + lane];
        int s0 = v0;
#pragma unroll
        for (int o = 1; o < 64; o <<= 1) { int t0 = __shfl_up(s0, o); if (lane >= o) s0 += t0; }
        int tot0 = __shfl(s0, 63);
        int s1 = v1;
#pragma unroll
        for (int o = 1; o < 64; o <<= 1) { int t1 = __shfl_up(s1, o); if (lane >= o) s1 += t1; }
        cbase[lane] = s0 - v0;
        cbase[64 + lane] = tot0 + s1 - v1;
        if (lane == 63) {
            counts[c] = tot0 + s1;
            int g = c + ltred[0] + ltred[1] + ltred[2] + ltred[3];
            gofs[c] = g;
            gsh = g;
        }
    }
    __syncthreads();
    int g = gsh;
    for (int ch = wave; ch < 128; ch += 4) {
        int m = ch * 64 + lane;
        bool match = (labs[m] == c);
        unsigned long long mask = __ballot(match);
        int pre = __popcll(mask & ((1ull << lane) - 1ull));
        if (match) perm[m] = g + 1 + cbase[ch] + pre;
    }
    for (int t = tid; t < D; t += 256)
        xgb[(size_t)g * D + t] = __float2bfloat16(cdic[c * D + t]);
}

// ---------------- K1: LayerNorm + bf16 scatter (round-3 proven) -----------------
__global__ __launch_bounds__(256) void k1_layernorm(const float* __restrict__ x,
        const float* __restrict__ gamma, const float* __restrict__ beta,
        const int* __restrict__ perm, __hip_bfloat16* __restrict__ xgb) {
    int wave = threadIdx.x >> 6;
    int lane = threadIdx.x & 63;
    int row = blockIdx.x * 4 + wave;
    const float* xr = x + (size_t)row * D;
    float4 v[3];
    float s = 0.f, sq = 0.f;
#pragma unroll
    for (int t = 0; t < 3; ++t) {
        v[t] = *(const float4*)(xr + (lane + 64 * t) * 4);
        s  += v[t].x + v[t].y + v[t].z + v[t].w;
        sq += v[t].x * v[t].x + v[t].y * v[t].y + v[t].z * v[t].z + v[t].w * v[t].w;
    }
#pragma unroll
    for (int o = 32; o; o >>= 1) { s += __shfl_xor(s, o); sq += __shfl_xor(sq, o); }
    float mu   = s / (float)D;
    float var  = sq / (float)D - mu * mu;
    float rstd = rsqrtf(var + EPS);
    int dest = perm[row];
    unsigned short* orow = (unsigned short*)xgb + (size_t)dest * D;
#pragma unroll
    for (int t = 0; t < 3; ++t) {
        int base = (lane + 64 * t) * 4;
        float4 g4 = *(const float4*)(gamma + base);
        float4 b4 = *(const float4*)(beta + base);
        float f0 = (v[t].x - mu) * rstd * g4.x + b4.x;
        float f1 = (v[t].y - mu) * rstd * g4.y + b4.y;
        float f2 = (v[t].z - mu) * rstd * g4.z + b4.z;
        float f3 = (v[t].w - mu) * rstd * g4.w + b4.w;
        __hip_bfloat16 h0 = __float2bfloat16(f0), h1 = __float2bfloat16(f1);
        __hip_bfloat16 h2 = __float2bfloat16(f2), h3 = __float2bfloat16(f3);
        ushort4 u;
        u.x = *(unsigned short*)&h0; u.y = *(unsigned short*)&h1;
        u.z = *(unsigned short*)&h2; u.w = *(unsigned short*)&h3;
        *(ushort4*)(orow + base) = u;
    }
}

// ------- kBC (512 thr, 191 blocks — ALL resident): gram(0..95) || cd->neg(96..190)
// cd blocks repurpose into neg blocks after publishing; last neg finisher waits
// for gram ticket and emits the loss. Producers never wait; every block is
// resident from t=0 (191 < 256 CUs, 1 block/CU) -> no scheduling staircase.
__global__ __launch_bounds__(512) void kBC(const __hip_bfloat16* __restrict__ xgbh,
        const float* __restrict__ cdic, const float* __restrict__ gamma,
        const float* __restrict__ beta, const int* __restrict__ counts,
        const int* __restrict__ gofs, float* __restrict__ posp,
        float* __restrict__ cd, unsigned int* __restrict__ negbits,
        unsigned int* __restrict__ tick, float* __restrict__ out) {
    int bid = blockIdx.x, tid = threadIdx.x, wave = tid >> 6, lane = tid & 63;

    if (bid < NCLS) {
        // -------- positive gram (r11 proven 8-wave body) --------
        const unsigned short* xgb = (const unsigned short*)xgbh;
        int c = bid;
        extern __shared__ unsigned short sh[];
        int r0 = gofs[c];
        int nc = counts[c] + 1;
        int ntile = (nc + 31) >> 5;
        int nr = ntile << 5;
        int tott = ntile * (ntile + 1) / 2;
        int s_ti[2], s_tj[2];
#pragma unroll
        for (int slot = 0; slot < 2; ++slot) {
            int t = wave + slot * 8;
            int ti = 0, rem = t, span = ntile;
            if (t < tott) {
                while (rem >= span) { rem -= span; --span; ++ti; }
                s_ti[slot] = ti; s_tj[slot] = ti + rem;
            } else { s_ti[slot] = 0; s_tj[slot] = 0; }
        }
        int r16 = lane & 15, sA = lane >> 4;
        int xr = r16 & 7;
        int e0 = (sA ^ xr) * 8;
        int e1 = ((sA + 4) ^ xr) * 8;
        f32x4 acc[2][4];
#pragma unroll
        for (int s = 0; s < 2; ++s)
#pragma unroll
            for (int q = 0; q < 4; ++q) acc[s][q] = f32x4{0.f, 0.f, 0.f, 0.f};
        for (int kc = 0; kc < D; kc += KB) {
            __syncthreads();
            int totseg = nr * SEGR;
            for (int seg = tid; seg < totseg; seg += 512) {
                int r = seg / SEGR, s = seg - r * SEGR;
                uint4 v = {0u, 0u, 0u, 0u};
                if (r < nc)
                    v = *(const uint4*)(xgb + (size_t)(r0 + r) * D + kc + s * 8);
                *(uint4*)(sh + r * KB + (s ^ (r & 7)) * 8) = v;
            }
            __syncthreads();
#pragma unroll
            for (int slot = 0; slot < 2; ++slot) {
                if (wave + slot * 8 >= tott) continue;
                int ti = s_ti[slot], tj = s_tj[slot];
                const unsigned short* pa0 = sh + (ti * 32 + r16) * KB;
                const unsigned short* pa1 = pa0 + 16 * KB;
                const unsigned short* pb0 = sh + (tj * 32 + r16) * KB;
                const unsigned short* pb1 = pb0 + 16 * KB;
#pragma unroll
                for (int ks = 0; ks < KB / 32; ++ks) {
                    int ko = (ks >> 1) * 64 + ((ks & 1) ? e1 : e0);
                    bf16x8 a0 = *(const bf16x8*)(pa0 + ko);
                    bf16x8 a1 = *(const bf16x8*)(pa1 + ko);
                    bf16x8 b0 = *(const bf16x8*)(pb0 + ko);
                    bf16x8 b1 = *(const bf16x8*)(pb1 + ko);
                    acc[slot][0] = __builtin_amdgcn_mfma_f32_16x16x32_bf16(a0, b0, acc[slot][0], 0, 0, 0);
                    acc[slot][1] = __builtin_amdgcn_mfma_f32_16x16x32_bf16(a0, b1, acc[slot][1], 0, 0, 0);
                    acc[slot][2] = __builtin_amdgcn_mfma_f32_16x16x32_bf16(a1, b0, acc[slot][2], 0, 0, 0);
                    acc[slot][3] = __builtin_amdgcn_mfma_f32_16x16x32_bf16(a1, b1, acc[slot][3], 0, 0, 0);
                }
            }
        }
        const float inv = 1.f / (float)D;
        float tacc = 0.f;
        int rbase = sA * 4;
#pragma unroll
        for (int slot = 0; slot < 2; ++slot) {
            if (wave + slot * 8 >= tott) continue;
            int ti = s_ti[slot], tj = s_tj[slot];
            float w = (ti == tj) ? 1.f : 2.f;
#pragma unroll
            for (int fa = 0; fa < 2; ++fa)
#pragma unroll
                for (int fb = 0; fb < 2; ++fb)
#pragma unroll
                    for (int reg = 0; reg < 4; ++reg) {
                        int i = ti * 32 + fa * 16 + rbase + reg;
                        int j = tj * 32 + fb * 16 + r16;
                        if (i < nc && j < nc)
                            tacc += w * __expf(acc[slot][fa * 2 + fb][reg] * inv);
                    }
        }
#pragma unroll
        for (int o = 32; o; o >>= 1) tacc += __shfl_xor(tacc, o);
        __syncthreads();
        float* red = (float*)sh;
        if (lane == 0) red[wave] = tacc;
        __syncthreads();
        if (tid == 0) {
            posp[c] = ((red[0] + red[1]) + (red[2] + red[3]))
                    + ((red[4] + red[5]) + (red[6] + red[7]));
            __threadfence();               // release posp
            atomicAdd(&tick[2], 1u);
        }
    } else {
        // -------- cd rows (r11 proven 8-wave body), then repurpose to neg -------
        int c = bid - 95;            // 1..95
        int n = counts[c];
        const unsigned short* rows = (const unsigned short*)xgbh + (size_t)(gofs[c] + 1) * D;
        float acc[3][4];
#pragma unroll
        for (int p = 0; p < 3; ++p)
#pragma unroll
            for (int e = 0; e < 4; ++e) acc[p][e] = 0.f;
        for (int r = wave; r < n; r += 8) {
            const unsigned short* rp = rows + (size_t)r * D + lane * 4;
#pragma unroll
            for (int p = 0; p < 3; ++p) {
                ushort4 u = *(const ushort4*)(rp + 256 * p);
                acc[p][0] += __bfloat162float(*(const __hip_bfloat16*)&u.x);
                acc[p][1] += __bfloat162float(*(const __hip_bfloat16*)&u.y);
                acc[p][2] += __bfloat162float(*(const __hip_bfloat16*)&u.z);
                acc[p][3] += __bfloat162float(*(const __hip_bfloat16*)&u.w);
            }
        }
        __shared__ float part[8][D];   // 24 KB static
        __shared__ float red[8];
        __shared__ int winner;
#pragma unroll
        for (int p = 0; p < 3; ++p)
#pragma unroll
            for (int e = 0; e < 4; ++e)
                part[wave][p * 256 + lane * 4 + e] = acc[p][e];
        __syncthreads();
        float u0 = 0.f, u1 = 0.f, u2 = 0.f;
        if (tid < 256) {
            float s0 = 0.f, s1 = 0.f, s2 = 0.f;
#pragma unroll
            for (int w = 0; w < 8; ++w) {
                s0 += part[w][tid];
                s1 += part[w][tid + 256];
                s2 += part[w][tid + 512];
            }
            float invn = 1.f / ((float)n + 1.f);
            float c0 = cdic[c * D + tid], c1 = cdic[c * D + tid + 256], c2v = cdic[c * D + tid + 512];
            u0 = c0 + 0.1f * (c0 + s0) * invn;
            u1 = c1 + 0.1f * (c1 + s1) * invn;
            u2 = c2v + 0.1f * (c2v + s2) * invn;
            float s = u0 + u1 + u2, sq = u0 * u0 + u1 * u1 + u2 * u2;
#pragma unroll
            for (int o = 32; o; o >>= 1) { s += __shfl_xor(s, o); sq += __shfl_xor(sq, o); }
            if (lane == 0) { red[wave] = s; red[4 + wave] = sq; }
        }
        __syncthreads();
        if (tid == 0) {
            red[0] = red[0] + red[1] + red[2] + red[3];
            red[4] = red[4] + red[5] + red[6] + red[7];
        }
        __syncthreads();
        if (tid < 256) {
            float mu   = red[0] / (float)D;
            float var  = red[4] / (float)D - mu * mu;
            float rstd = rsqrtf(var + EPS);
            float* outr = cd + (size_t)(c - 1) * D;
            outr[tid]       = (u0 - mu) * rstd * gamma[tid]       + beta[tid];
            outr[tid + 256] = (u1 - mu) * rstd * gamma[tid + 256] + beta[tid + 256];
            outr[tid + 512] = (u2 - mu) * rstd * gamma[tid + 512] + beta[tid + 512];
        }
        __syncthreads();               // all cd stores issued
        if (tid == 0) {
            __threadfence();           // release cd row
            atomicAdd(&tick[1], 1u);
            while (atomicOr(&tick[1], 0u) < 95u) __builtin_amdgcn_s_sleep(8);
            winner = 0;
        }
        __syncthreads();
        __threadfence();               // acquire all cd rows

        // -------- neg gram for row i = c-1 (r12 body; rowi reuses part[0]) ------
        int i = c - 1;                 // 0..94
        float* rowi = &part[0][0];
        for (int t = tid; t < D; t += 512) rowi[t] = cd[(size_t)i * D + t];
        __syncthreads();
        float nacc = 0.f;
        for (int j = wave; j < 95; j += 8) {
            const float* rj = cd + (size_t)j * D;
            float dot = 0.f;
#pragma unroll
            for (int t = 0; t < 12; ++t) dot += rowi[lane + 64 * t] * rj[lane + 64 * t];
#pragma unroll
            for (int o = 32; o; o >>= 1) dot += __shfl_xor(dot, o);
            if (lane == 0) nacc += __expf(dot * (1.f / (float)D));
        }
        __syncthreads();
        if (lane == 0) red[wave] = nacc;
        __syncthreads();
        if (tid == 0) {
            float val = ((red[0] + red[1]) + (red[2] + red[3]))
                      + ((red[4] + red[5]) + (red[6] + red[7]));
            atomicExch(&negbits[i], __float_as_uint(val));   // publish
            __threadfence();
            winner = (atomicAdd(&tick[0], 1u) == 94u) ? 1 : 0;
        }
        __syncthreads();
        if (winner && wave == 0) {
            if (lane == 0)
                while (atomicOr(&tick[2], 0u) < (unsigned)NCLS)  // wait gram posp
                    __builtin_amdgcn_s_sleep(8);
            __shfl(0, 0);              // wave-converged after lane0 poll
            __threadfence();           // acquire posp + negbits
            double ng = (lane < 95)
                ? (double)__uint_as_float(atomicOr(&negbits[lane], 0u)) : 0.0;
            if (lane < 31)
                ng += (double)__uint_as_float(atomicOr(&negbits[64 + lane], 0u));
            double p = (double)posp[lane];
            if (lane < 32) p += (double)posp[64 + lane];
#pragma unroll
            for (int o = 32; o; o >>= 1) {
                ng += __shfl_xor(ng, o);
                p  += __shfl_xor(p, o);
            }
            if (lane == 0) out[0] = (float)(log(ng) - log(p));
        }
    }
}

extern "C" void kernel_launch(void* const* d_in, const int* in_sizes, int n_in,
                              void* d_out, int out_size, void* d_ws, size_t ws_size,
                              hipStream_t stream) {
    const float* input_f  = (const float*)d_in[0];
    const float* char_dic = (const float*)d_in[1];
    const float* gamma    = (const float*)d_in[2];
    const float* beta     = (const float*)d_in[3];
    const int*   target   = (const int*)d_in[4];
    float* out = (float*)d_out;

    char* ws = (char*)d_ws;
    size_t off = 0;
    auto carve = [&](size_t bytes) -> void* {
        void* p = ws + off;
        off = (off + bytes + 255) & ~(size_t)255;
        return p;
    };
    __hip_bfloat16* xgb = (__hip_bfloat16*)carve((size_t)(NROWS + 32) * D * 2); // 12.8 MB
    int*          perm    = (int*)  carve((size_t)M * 4);
    int*          counts  = (int*)  carve(NCLS * 4);
    int*          gofs    = (int*)  carve(NCLS * 4);
    float*        posp    = (float*)carve(NCLS * 4);
    float*        cd      = (float*)carve((size_t)95 * D * 4);
    unsigned int* negbits = (unsigned int*)carve(95 * 4);
    unsigned int* tick    = (unsigned int*)carve(64);

    (void)hipFuncSetAttribute((const void*)kBC,
            hipFuncAttributeMaxDynamicSharedMemorySize, DYN_B);

    k2_lists<<<NCLS, 256, 0, stream>>>(target, char_dic, perm, counts, gofs, xgb, tick);
    k1_layernorm<<<M / 4, 256, 0, stream>>>(input_f, gamma, beta, perm, xgb);
    kBC<<<NCLS + 95, 512, DYN_B, stream>>>(xgb, char_dic, gamma, beta,
            counts, gofs, posp, cd, negbits, tick, out);
}

// Round 14
// 70.379 us; speedup vs baseline: 1.0534x; 1.0534x over previous
//
#include <hip/hip_runtime.h>
#include <hip/hip_bf16.h>
#include <math.h>

#define D 768
#define NCLS 96
#define M 8192            // 32*256 tokens
#define NROWS (M + NCLS)  // 8288 grouped rows
#define EPS 1e-5f

#define MAXR 160          // max rows per class (dict + tokens)
#define TPC 15            // max tile-pairs per class (ntile<=5)
#define NPT (NCLS * TPC)  // 1440 postile entries
#define DYN_B (2 * 32 * D * 2)   // two 32-row bf16 tiles = 98304 B dynamic LDS

typedef __attribute__((ext_vector_type(8))) short bf16x8;
typedef __attribute__((ext_vector_type(4))) float f32x4;

// ---------------- K2: counts/gofs/perm + dict copy (round-3 proven) -------------
__global__ __launch_bounds__(256) void k2_lists(const int* __restrict__ labels,
        const float* __restrict__ cdic, int* __restrict__ perm,
        int* __restrict__ counts, int* __restrict__ gofs,
        __hip_bfloat16* __restrict__ xgb, unsigned int* __restrict__ tick) {
    int c = blockIdx.x;
    int tid = threadIdx.x, wave = tid >> 6, lane = tid & 63;
    __shared__ int labs[M];
    __shared__ int ccnt[128];
    __shared__ int cbase[128];
    __shared__ int ltred[4];
    __shared__ int gsh;
    if (c == 0 && tid == 0) tick[0] = 0u;     // reset winner ticket each call
    for (int t = tid; t < M / 4; t += 256)
        ((int4*)labs)[t] = ((const int4*)labels)[t];
    __syncthreads();
    int lt0 = 0;
    for (int ch = wave; ch < 128; ch += 4) {
        int lab = labs[ch * 64 + lane];
        unsigned long long meq = __ballot(lab == c);
        unsigned long long mlt = __ballot(lab < c);
        if (lane == 0) { ccnt[ch] = __popcll(meq); lt0 += __popcll(mlt); }
    }
    if (lane == 0) ltred[wave] = lt0;
    __syncthreads();
    if (wave == 0) {
        int v0 = ccnt[lane], v1 = ccnt[64 + lane];
        int s0 = v0;
#pragma unroll
        for (int o = 1; o < 64; o <<= 1) { int t0 = __shfl_up(s0, o); if (lane >= o) s0 += t0; }
        int tot0 = __shfl(s0, 63);
        int s1 = v1;
#pragma unroll
        for (int o = 1; o < 64; o <<= 1) { int t1 = __shfl_up(s1, o); if (lane >= o) s1 += t1; }
        cbase[lane] = s0 - v0;
        cbase[64 + lane] = tot0 + s1 - v1;
        if (lane == 63) {
            counts[c] = tot0 + s1;
            int g = c + ltred[0] + ltred[1] + ltred[2] + ltred[3];
            gofs[c] = g;
            gsh = g;
        }
    }
    __syncthreads();
    int g = gsh;
    for (int ch = wave; ch < 128; ch += 4) {
        int m = ch * 64 + lane;
        bool match = (labs[m] == c);
        unsigned long long mask = __ballot(match);
        int pre = __popcll(mask & ((1ull << lane) - 1ull));
        if (match) perm[m] = g + 1 + cbase[ch] + pre;
    }
    for (int t = tid; t < D; t += 256)
        xgb[(size_t)g * D + t] = __float2bfloat16(cdic[c * D + t]);
}

// ---------------- K1: LayerNorm + bf16 scatter (round-3 proven) -----------------
__global__ __launch_bounds__(256) void k1_layernorm(const float* __restrict__ x,
        const float* __restrict__ gamma, const float* __restrict__ beta,
        const int* __restrict__ perm, __hip_bfloat16* __restrict__ xgb) {
    int wave = threadIdx.x >> 6;
    int lane = threadIdx.x & 63;
    int row = blockIdx.x * 4 + wave;
    const float* xr = x + (size_t)row * D;
    float4 v[3];
    float s = 0.f, sq = 0.f;
#pragma unroll
    for (int t = 0; t < 3; ++t) {
        v[t] = *(const float4*)(xr + (lane + 64 * t) * 4);
        s  += v[t].x + v[t].y + v[t].z + v[t].w;
        sq += v[t].x * v[t].x + v[t].y * v[t].y + v[t].z * v[t].z + v[t].w * v[t].w;
    }
#pragma unroll
    for (int o = 32; o; o >>= 1) { s += __shfl_xor(s, o); sq += __shfl_xor(sq, o); }
    float mu   = s / (float)D;
    float var  = sq / (float)D - mu * mu;
    float rstd = rsqrtf(var + EPS);
    int dest = perm[row];
    unsigned short* orow = (unsigned short*)xgb + (size_t)dest * D;
#pragma unroll
    for (int t = 0; t < 3; ++t) {
        int base = (lane + 64 * t) * 4;
        float4 g4 = *(const float4*)(gamma + base);
        float4 b4 = *(const float4*)(beta + base);
        float f0 = (v[t].x - mu) * rstd * g4.x + b4.x;
        float f1 = (v[t].y - mu) * rstd * g4.y + b4.y;
        float f2 = (v[t].z - mu) * rstd * g4.z + b4.z;
        float f3 = (v[t].w - mu) * rstd * g4.w + b4.w;
        __hip_bfloat16 h0 = __float2bfloat16(f0), h1 = __float2bfloat16(f1);
        __hip_bfloat16 h2 = __float2bfloat16(f2), h3 = __float2bfloat16(f3);
        ushort4 u;
        u.x = *(unsigned short*)&h0; u.y = *(unsigned short*)&h1;
        u.z = *(unsigned short*)&h2; u.w = *(unsigned short*)&h3;
        *(ushort4*)(orow + base) = u;
    }
}

// ------- kB (256 thr): per-tile-pair gram (0..1439) || cd (1440..1534) ----------
// One block per (class, upper-tri 32x32 tile pair). K=768 staged once (2 tiles,
// 96 KB); 4 waves split K, partial tiles LDS-reduced in fixed order. ~671 real
// blocks fill the chip; excess pairs write 0 and retire. No cross-block sync.
__global__ __launch_bounds__(256) void kB(const __hip_bfloat16* __restrict__ xgbh,
        const float* __restrict__ cdic, const float* __restrict__ gamma,
        const float* __restrict__ beta, const int* __restrict__ counts,
        const int* __restrict__ gofs, float* __restrict__ postile,
        float* __restrict__ cd) {
    int bid = blockIdx.x, tid = threadIdx.x, wave = tid >> 6, lane = tid & 63;
    __shared__ float spart[8][D];    // gram: [4][1024] partials; cd: [4][768]
    __shared__ float red[8];

    if (bid < NPT) {
        // -------- gram tile-pair --------
        int c = bid / TPC, p = bid % TPC;
        int nc = counts[c] + 1;
        int ntile = (nc + 31) >> 5;
        int tott = ntile * (ntile + 1) / 2;
        if (p >= tott) { if (tid == 0) postile[bid] = 0.f; return; }
        int ti = 0, rem = p, span = ntile;
        while (rem >= span) { rem -= span; --span; ++ti; }
        int tj = ti + rem;
        int r0 = gofs[c];
        const unsigned short* xgb = (const unsigned short*)xgbh;
        extern __shared__ unsigned short sh[];   // tileA[32*768], tileB[32*768]
        unsigned short* shA = sh;
        unsigned short* shB = sh + 32 * D;
        int hasB = (ti != tj);
        // stage: 1536 segs/tile, 16B each, XOR-swizzled within each row
        for (int q = tid; q < 1536; q += 256) {
            int r = q / 48, s = q - r * 48;
            int sw = (s ^ (r & 7)) * 8;
            int ra = ti * 32 + r;
            uint4 va = {0u, 0u, 0u, 0u};
            if (ra < nc) va = *(const uint4*)(xgb + (size_t)(r0 + ra) * D + s * 8);
            *(uint4*)(shA + r * D + sw) = va;
            if (hasB) {
                int rb = tj * 32 + r;
                uint4 vb = {0u, 0u, 0u, 0u};
                if (rb < nc) vb = *(const uint4*)(xgb + (size_t)(r0 + rb) * D + s * 8);
                *(uint4*)(shB + r * D + sw) = vb;
            }
        }
        if (!hasB) shB = shA;
        __syncthreads();
        // MFMA: wave w covers ks in [w*6, w*6+6)  (24 K-steps total = K=768)
        int r16 = lane & 15, sA = lane >> 4;
        int xr = r16 & 7;
        const unsigned short* pa0 = shA + r16 * D;
        const unsigned short* pa1 = pa0 + 16 * D;
        const unsigned short* pb0 = shB + r16 * D;
        const unsigned short* pb1 = pb0 + 16 * D;
        f32x4 acc[4];
#pragma unroll
        for (int q = 0; q < 4; ++q) acc[q] = f32x4{0.f, 0.f, 0.f, 0.f};
#pragma unroll
        for (int k = 0; k < 6; ++k) {
            int ks = wave * 6 + k;
            int ko = ((ks * 4 + sA) ^ xr) * 8;
            bf16x8 a0 = *(const bf16x8*)(pa0 + ko);
            bf16x8 a1 = *(const bf16x8*)(pa1 + ko);
            bf16x8 b0 = *(const bf16x8*)(pb0 + ko);
            bf16x8 b1 = *(const bf16x8*)(pb1 + ko);
            acc[0] = __builtin_amdgcn_mfma_f32_16x16x32_bf16(a0, b0, acc[0], 0, 0, 0);
            acc[1] = __builtin_amdgcn_mfma_f32_16x16x32_bf16(a0, b1, acc[1], 0, 0, 0);
            acc[2] = __builtin_amdgcn_mfma_f32_16x16x32_bf16(a1, b0, acc[2], 0, 0, 0);
            acc[3] = __builtin_amdgcn_mfma_f32_16x16x32_bf16(a1, b1, acc[3], 0, 0, 0);
        }
        // write per-wave partial 32x32 tile (C/D: col=lane&15, row=(lane>>4)*4+reg)
        float* pr = (float*)spart;               // [4][1024]
#pragma unroll
        for (int fa = 0; fa < 2; ++fa)
#pragma unroll
            for (int fb = 0; fb < 2; ++fb)
#pragma unroll
                for (int reg = 0; reg < 4; ++reg) {
                    int il = fa * 16 + sA * 4 + reg;
                    int jl = fb * 16 + r16;
                    pr[wave * 1024 + il * 32 + jl] = acc[fa * 2 + fb][reg];
                }
        __syncthreads();
        // reduce 4 wave-partials (fixed order), mask, exp, block-reduce
        const float inv = 1.f / (float)D;
        float wgt = (ti == tj) ? 1.f : 2.f;
        float tacc = 0.f;
#pragma unroll
        for (int e = tid * 4; e < tid * 4 + 4; ++e) {
            float dv = (pr[e] + pr[1024 + e]) + (pr[2048 + e] + pr[3072 + e]);
            int gi = ti * 32 + (e >> 5), gj = tj * 32 + (e & 31);
            if (gi < nc && gj < nc) tacc += wgt * __expf(dv * inv);
        }
#pragma unroll
        for (int o = 32; o; o >>= 1) tacc += __shfl_xor(tacc, o);
        if (lane == 0) red[wave] = tacc;
        __syncthreads();
        if (tid == 0) postile[bid] = (red[0] + red[1]) + (red[2] + red[3]);
    } else {
        // -------- cd rows (r8 proven 256-thr body), c = bid-NPT+1 in 1..95 ------
        int c = bid - NPT + 1;
        int n = counts[c];
        const unsigned short* rows = (const unsigned short*)xgbh + (size_t)(gofs[c] + 1) * D;
        float acc[3][4];
#pragma unroll
        for (int p = 0; p < 3; ++p)
#pragma unroll
            for (int e = 0; e < 4; ++e) acc[p][e] = 0.f;
        for (int r = wave; r < n; r += 4) {
            const unsigned short* rp = rows + (size_t)r * D + lane * 4;
#pragma unroll
            for (int p = 0; p < 3; ++p) {
                ushort4 u = *(const ushort4*)(rp + 256 * p);
                acc[p][0] += __bfloat162float(*(const __hip_bfloat16*)&u.x);
                acc[p][1] += __bfloat162float(*(const __hip_bfloat16*)&u.y);
                acc[p][2] += __bfloat162float(*(const __hip_bfloat16*)&u.z);
                acc[p][3] += __bfloat162float(*(const __hip_bfloat16*)&u.w);
            }
        }
#pragma unroll
        for (int p = 0; p < 3; ++p)
#pragma unroll
            for (int e = 0; e < 4; ++e)
                spart[wave][p * 256 + lane * 4 + e] = acc[p][e];
        __syncthreads();
        float s0 = (spart[0][tid] + spart[1][tid]) + (spart[2][tid] + spart[3][tid]);
        float s1 = (spart[0][tid + 256] + spart[1][tid + 256]) + (spart[2][tid + 256] + spart[3][tid + 256]);
        float s2 = (spart[0][tid + 512] + spart[1][tid + 512]) + (spart[2][tid + 512] + spart[3][tid + 512]);
        float invn = 1.f / ((float)n + 1.f);
        float c0 = cdic[c * D + tid], c1 = cdic[c * D + tid + 256], c2v = cdic[c * D + tid + 512];
        float u0 = c0 + 0.1f * (c0 + s0) * invn;
        float u1 = c1 + 0.1f * (c1 + s1) * invn;
        float u2 = c2v + 0.1f * (c2v + s2) * invn;
        float s = u0 + u1 + u2, sq = u0 * u0 + u1 * u1 + u2 * u2;
#pragma unroll
        for (int o = 32; o; o >>= 1) { s += __shfl_xor(s, o); sq += __shfl_xor(sq, o); }
        if (lane == 0) { red[wave] = s; red[4 + wave] = sq; }
        __syncthreads();
        if (tid == 0) {
            red[0] = red[0] + red[1] + red[2] + red[3];
            red[4] = red[4] + red[5] + red[6] + red[7];
        }
        __syncthreads();
        float mu   = red[0] / (float)D;
        float var  = red[4] / (float)D - mu * mu;
        float rstd = rsqrtf(var + EPS);
        float* outr = cd + (size_t)(c - 1) * D;
        outr[tid]       = (u0 - mu) * rstd * gamma[tid]       + beta[tid];
        outr[tid + 256] = (u1 - mu) * rstd * gamma[tid + 256] + beta[tid + 256];
        outr[tid + 512] = (u2 - mu) * rstd * gamma[tid + 512] + beta[tid + 512];
    }
}

// ---------------- kC: neg gram + ticket-gated final loss (proven r6-r11) --------
__global__ __launch_bounds__(256) void kC(const float* __restrict__ cd,
        const float* __restrict__ postile, unsigned int* __restrict__ negbits,
        unsigned int* __restrict__ tick, float* __restrict__ out) {
    int i = blockIdx.x;    // 0..94
    int tid = threadIdx.x, wave = tid >> 6, lane = tid & 63;
    __shared__ float rowi[D];
    __shared__ float red[4];
    __shared__ int winner;
    for (int t = tid; t < D; t += 256) rowi[t] = cd[(size_t)i * D + t];
    __syncthreads();
    float acc = 0.f;
    for (int j = wave; j < 95; j += 4) {
        const float* rj = cd + (size_t)j * D;
        float dot = 0.f;
#pragma unroll
        for (int t = 0; t < 12; ++t) dot += rowi[lane + 64 * t] * rj[lane + 64 * t];
#pragma unroll
        for (int o = 32; o; o >>= 1) dot += __shfl_xor(dot, o);
        if (lane == 0) acc += __expf(dot * (1.f / (float)D));
    }
    if (lane == 0) red[wave] = acc;
    __syncthreads();
    if (tid == 0) {
        float val = red[0] + red[1] + red[2] + red[3];
        atomicExch(&negbits[i], __float_as_uint(val));   // device-scope publish
        __threadfence();
        winner = (atomicAdd(&tick[0], 1u) == 94u) ? 1 : 0; // 95th finisher wins
    }
    __syncthreads();
    if (winner && wave == 0) {
        __threadfence();                                 // acquire others' publishes
        double ng = (lane < 95)
            ? (double)__uint_as_float(atomicOr(&negbits[lane], 0u)) : 0.0;
        if (lane < 31)
            ng += (double)__uint_as_float(atomicOr(&negbits[64 + lane], 0u));
        double p = 0.0;
        for (int t = lane; t < NPT; t += 64) p += (double)postile[t];
#pragma unroll
        for (int o = 32; o; o >>= 1) {
            ng += __shfl_xor(ng, o);
            p  += __shfl_xor(p, o);
        }
        if (lane == 0) out[0] = (float)(log(ng) - log(p));
    }
}

extern "C" void kernel_launch(void* const* d_in, const int* in_sizes, int n_in,
                              void* d_out, int out_size, void* d_ws, size_t ws_size,
                              hipStream_t stream) {
    const float* input_f  = (const float*)d_in[0];
    const float* char_dic = (const float*)d_in[1];
    const float* gamma    = (const float*)d_in[2];
    const float* beta     = (const float*)d_in[3];
    const int*   target   = (const int*)d_in[4];
    float* out = (float*)d_out;

    char* ws = (char*)d_ws;
    size_t off = 0;
    auto carve = [&](size_t bytes) -> void* {
        void* p = ws + off;
        off = (off + bytes + 255) & ~(size_t)255;
        return p;
    };
    __hip_bfloat16* xgb = (__hip_bfloat16*)carve((size_t)(NROWS + 32) * D * 2); // 12.8 MB
    int*          perm    = (int*)  carve((size_t)M * 4);
    int*          counts  = (int*)  carve(NCLS * 4);
    int*          gofs    = (int*)  carve(NCLS * 4);
    float*        postile = (float*)carve(NPT * 4);
    float*        cd      = (float*)carve((size_t)95 * D * 4);
    unsigned int* negbits = (unsigned int*)carve(95 * 4);
    unsigned int* tick    = (unsigned int*)carve(64);

    (void)hipFuncSetAttribute((const void*)kB,
            hipFuncAttributeMaxDynamicSharedMemorySize, DYN_B);

    k2_lists<<<NCLS, 256, 0, stream>>>(target, char_dic, perm, counts, gofs, xgb, tick);
    k1_layernorm<<<M / 4, 256, 0, stream>>>(input_f, gamma, beta, perm, xgb);
    kB<<<NPT + 95, 256, DYN_B, stream>>>(xgb, char_dic, gamma, beta,
            counts, gofs, postile, cd);
    kC<<<95, 256, 0, stream>>>(cd, postile, negbits, tick, out);
}

// Round 15
// 50.664 us; speedup vs baseline: 1.4633x; 1.3891x over previous
//
#include <hip/hip_runtime.h>
#include <hip/hip_bf16.h>
#include <math.h>

#define D 768
#define NCLS 96
#define M 8192            // 32*256 tokens
#define NROWS (M + NCLS)  // 8288 grouped rows
#define EPS 1e-5f

// gram geometry (proven round-3/11)
#define KB 384
#define SEGR 48           // KB/8 16B segments per row-chunk
#define MAXR 160          // max rows per class (dict + tokens)
#define DYN_B (MAXR * KB * 2)   // 122880 B dynamic LDS

typedef __attribute__((ext_vector_type(8))) short bf16x8;
typedef __attribute__((ext_vector_type(4))) float f32x4;

// ---------------- K2: counts/gofs/perm + dict copy (round-3 proven) -------------
__global__ __launch_bounds__(256) void k2_lists(const int* __restrict__ labels,
        const float* __restrict__ cdic, int* __restrict__ perm,
        int* __restrict__ counts, int* __restrict__ gofs,
        __hip_bfloat16* __restrict__ xgb, unsigned int* __restrict__ tick) {
    int c = blockIdx.x;
    int tid = threadIdx.x, wave = tid >> 6, lane = tid & 63;
    __shared__ int labs[M];
    __shared__ int ccnt[128];
    __shared__ int cbase[128];
    __shared__ int ltred[4];
    __shared__ int gsh;
    if (c == 0 && tid == 0) tick[0] = 0u;     // reset winner ticket each call
    for (int t = tid; t < M / 4; t += 256)
        ((int4*)labs)[t] = ((const int4*)labels)[t];
    __syncthreads();
    int lt0 = 0;
    for (int ch = wave; ch < 128; ch += 4) {
        int lab = labs[ch * 64 + lane];
        unsigned long long meq = __ballot(lab == c);
        unsigned long long mlt = __ballot(lab < c);
        if (lane == 0) { ccnt[ch] = __popcll(meq); lt0 += __popcll(mlt); }
    }
    if (lane == 0) ltred[wave] = lt0;
    __syncthreads();
    if (wave == 0) {
        int v0 = ccnt[lane], v1 = ccnt[64 + lane];
        int s0 = v0;
#pragma unroll
        for (int o = 1; o < 64; o <<= 1) { int t0 = __shfl_up(s0, o); if (lane >= o) s0 += t0; }
        int tot0 = __shfl(s0, 63);
        int s1 = v1;
#pragma unroll
        for (int o = 1; o < 64; o <<= 1) { int t1 = __shfl_up(s1, o); if (lane >= o) s1 += t1; }
        cbase[lane] = s0 - v0;
        cbase[64 + lane] = tot0 + s1 - v1;
        if (lane == 63) {
            counts[c] = tot0 + s1;
            int g = c + ltred[0] + ltred[1] + ltred[2] + ltred[3];
            gofs[c] = g;
            gsh = g;
        }
    }
    __syncthreads();
    int g = gsh;
    for (int ch = wave; ch < 128; ch += 4) {
        int m = ch * 64 + lane;
        bool match = (labs[m] == c);
        unsigned long long mask = __ballot(match);
        int pre = __popcll(mask & ((1ull << lane) - 1ull));
        if (match) perm[m] = g + 1 + cbase[ch] + pre;
    }
    for (int t = tid; t < D; t += 256)
        xgb[(size_t)g * D + t] = __float2bfloat16(cdic[c * D + t]);
}

// ---------------- K1: LayerNorm + bf16 scatter (round-3 proven) -----------------
__global__ __launch_bounds__(256) void k1_layernorm(const float* __restrict__ x,
        const float* __restrict__ gamma, const float* __restrict__ beta,
        const int* __restrict__ perm, __hip_bfloat16* __restrict__ xgb) {
    int wave = threadIdx.x >> 6;
    int lane = threadIdx.x & 63;
    int row = blockIdx.x * 4 + wave;
    const float* xr = x + (size_t)row * D;
    float4 v[3];
    float s = 0.f, sq = 0.f;
#pragma unroll
    for (int t = 0; t < 3; ++t) {
        v[t] = *(const float4*)(xr + (lane + 64 * t) * 4);
        s  += v[t].x + v[t].y + v[t].z + v[t].w;
        sq += v[t].x * v[t].x + v[t].y * v[t].y + v[t].z * v[t].z + v[t].w * v[t].w;
    }
#pragma unroll
    for (int o = 32; o; o >>= 1) { s += __shfl_xor(s, o); sq += __shfl_xor(sq, o); }
    float mu   = s / (float)D;
    float var  = sq / (float)D - mu * mu;
    float rstd = rsqrtf(var + EPS);
    int dest = perm[row];
    unsigned short* orow = (unsigned short*)xgb + (size_t)dest * D;
#pragma unroll
    for (int t = 0; t < 3; ++t) {
        int base = (lane + 64 * t) * 4;
        float4 g4 = *(const float4*)(gamma + base);
        float4 b4 = *(const float4*)(beta + base);
        float f0 = (v[t].x - mu) * rstd * g4.x + b4.x;
        float f1 = (v[t].y - mu) * rstd * g4.y + b4.y;
        float f2 = (v[t].z - mu) * rstd * g4.z + b4.z;
        float f3 = (v[t].w - mu) * rstd * g4.w + b4.w;
        __hip_bfloat16 h0 = __float2bfloat16(f0), h1 = __float2bfloat16(f1);
        __hip_bfloat16 h2 = __float2bfloat16(f2), h3 = __float2bfloat16(f3);
        ushort4 u;
        u.x = *(unsigned short*)&h0; u.y = *(unsigned short*)&h1;
        u.z = *(unsigned short*)&h2; u.w = *(unsigned short*)&h3;
        *(ushort4*)(orow + base) = u;
    }
}

// ---------------- kB (512 thr): gram (blocks 0..95) || cd (96..190) -------------
// r11 proven structure; staging now async global->LDS (width 16) with linear LDS
// dest + inverse-swizzled per-lane global source (m173 pattern). Pad rows read
// neighbor-class bytes; their accumulator entries are masked before exp.
__global__ __launch_bounds__(512) void kB(const __hip_bfloat16* __restrict__ xgbh,
        const float* __restrict__ cdic, const float* __restrict__ gamma,
        const float* __restrict__ beta, const int* __restrict__ counts,
        const int* __restrict__ gofs, float* __restrict__ posp,
        float* __restrict__ cd) {
    int bid = blockIdx.x, tid = threadIdx.x, wave = tid >> 6, lane = tid & 63;

    if (bid < NCLS) {
        // -------- positive gram (r11 8-wave body, async staging) --------
        const unsigned short* xgb = (const unsigned short*)xgbh;
        int c = bid;
        extern __shared__ unsigned short sh[];
        int r0 = gofs[c];
        int nc = counts[c] + 1;
        int ntile = (nc + 31) >> 5;
        int nr = ntile << 5;
        int tott = ntile * (ntile + 1) / 2;
        int s_ti[2], s_tj[2];
#pragma unroll
        for (int slot = 0; slot < 2; ++slot) {
            int t = wave + slot * 8;
            int ti = 0, rem = t, span = ntile;
            if (t < tott) {
                while (rem >= span) { rem -= span; --span; ++ti; }
                s_ti[slot] = ti; s_tj[slot] = ti + rem;
            } else { s_ti[slot] = 0; s_tj[slot] = 0; }
        }
        int r16 = lane & 15, sA = lane >> 4;
        int xr = r16 & 7;
        int e0 = (sA ^ xr) * 8;
        int e1 = ((sA + 4) ^ xr) * 8;
        f32x4 acc[2][4];
#pragma unroll
        for (int s = 0; s < 2; ++s)
#pragma unroll
            for (int q = 0; q < 4; ++q) acc[s][q] = f32x4{0.f, 0.f, 0.f, 0.f};
        for (int kc = 0; kc < D; kc += KB) {
            __syncthreads();
            int totseg = nr * SEGR;          // nr mult of 32 -> totseg mult of 1536
            // async: linear LDS dest (seg q), global src seg (q%48)^(r&7) of row q/48
            for (int qb = wave * 64; qb < totseg; qb += 512) {
                int q = qb + lane;
                int r = q / SEGR, s = q - r * SEGR;
                const unsigned short* src =
                    xgb + (size_t)(r0 + r) * D + kc + ((s ^ (r & 7)) << 3);
                __builtin_amdgcn_global_load_lds(
                    (const __attribute__((address_space(1))) unsigned int*)src,
                    (__attribute__((address_space(3))) unsigned int*)(sh + (size_t)qb * 8),
                    16, 0, 0);
            }
            __syncthreads();
#pragma unroll
            for (int slot = 0; slot < 2; ++slot) {
                if (wave + slot * 8 >= tott) continue;
                int ti = s_ti[slot], tj = s_tj[slot];
                const unsigned short* pa0 = sh + (ti * 32 + r16) * KB;
                const unsigned short* pa1 = pa0 + 16 * KB;
                const unsigned short* pb0 = sh + (tj * 32 + r16) * KB;
                const unsigned short* pb1 = pb0 + 16 * KB;
#pragma unroll
                for (int ks = 0; ks < KB / 32; ++ks) {
                    int ko = (ks >> 1) * 64 + ((ks & 1) ? e1 : e0);
                    bf16x8 a0 = *(const bf16x8*)(pa0 + ko);
                    bf16x8 a1 = *(const bf16x8*)(pa1 + ko);
                    bf16x8 b0 = *(const bf16x8*)(pb0 + ko);
                    bf16x8 b1 = *(const bf16x8*)(pb1 + ko);
                    acc[slot][0] = __builtin_amdgcn_mfma_f32_16x16x32_bf16(a0, b0, acc[slot][0], 0, 0, 0);
                    acc[slot][1] = __builtin_amdgcn_mfma_f32_16x16x32_bf16(a0, b1, acc[slot][1], 0, 0, 0);
                    acc[slot][2] = __builtin_amdgcn_mfma_f32_16x16x32_bf16(a1, b0, acc[slot][2], 0, 0, 0);
                    acc[slot][3] = __builtin_amdgcn_mfma_f32_16x16x32_bf16(a1, b1, acc[slot][3], 0, 0, 0);
                }
            }
        }
        const float inv = 1.f / (float)D;
        float tacc = 0.f;
        int rbase = sA * 4;
#pragma unroll
        for (int slot = 0; slot < 2; ++slot) {
            if (wave + slot * 8 >= tott) continue;
            int ti = s_ti[slot], tj = s_tj[slot];
            float w = (ti == tj) ? 1.f : 2.f;
#pragma unroll
            for (int fa = 0; fa < 2; ++fa)
#pragma unroll
                for (int fb = 0; fb < 2; ++fb)
#pragma unroll
                    for (int reg = 0; reg < 4; ++reg) {
                        int i = ti * 32 + fa * 16 + rbase + reg;
                        int j = tj * 32 + fb * 16 + r16;
                        if (i < nc && j < nc)
                            tacc += w * __expf(acc[slot][fa * 2 + fb][reg] * inv);
                    }
        }
#pragma unroll
        for (int o = 32; o; o >>= 1) tacc += __shfl_xor(tacc, o);
        __syncthreads();
        float* red = (float*)sh;
        if (lane == 0) red[wave] = tacc;
        __syncthreads();
        if (tid == 0)
            posp[c] = ((red[0] + red[1]) + (red[2] + red[3]))
                    + ((red[4] + red[5]) + (red[6] + red[7]));
    } else {
        // -------- cd rows (r11 proven 8-wave body) --------
        int c = bid - 95;            // 1..95
        int n = counts[c];
        const unsigned short* rows = (const unsigned short*)xgbh + (size_t)(gofs[c] + 1) * D;
        float acc[3][4];
#pragma unroll
        for (int p = 0; p < 3; ++p)
#pragma unroll
            for (int e = 0; e < 4; ++e) acc[p][e] = 0.f;
        for (int r = wave; r < n; r += 8) {
            const unsigned short* rp = rows + (size_t)r * D + lane * 4;
#pragma unroll
            for (int p = 0; p < 3; ++p) {
                ushort4 u = *(const ushort4*)(rp + 256 * p);
                acc[p][0] += __bfloat162float(*(const __hip_bfloat16*)&u.x);
                acc[p][1] += __bfloat162float(*(const __hip_bfloat16*)&u.y);
                acc[p][2] += __bfloat162float(*(const __hip_bfloat16*)&u.z);
                acc[p][3] += __bfloat162float(*(const __hip_bfloat16*)&u.w);
            }
        }
        __shared__ float part[8][D];   // 24 KB static
        __shared__ float red[8];
#pragma unroll
        for (int p = 0; p < 3; ++p)
#pragma unroll
            for (int e = 0; e < 4; ++e)
                part[wave][p * 256 + lane * 4 + e] = acc[p][e];
        __syncthreads();
        float u0 = 0.f, u1 = 0.f, u2 = 0.f;
        if (tid < 256) {
            float s0 = 0.f, s1 = 0.f, s2 = 0.f;
#pragma unroll
            for (int w = 0; w < 8; ++w) {
                s0 += part[w][tid];
                s1 += part[w][tid + 256];
                s2 += part[w][tid + 512];
            }
            float invn = 1.f / ((float)n + 1.f);
            float c0 = cdic[c * D + tid], c1 = cdic[c * D + tid + 256], c2v = cdic[c * D + tid + 512];
            u0 = c0 + 0.1f * (c0 + s0) * invn;
            u1 = c1 + 0.1f * (c1 + s1) * invn;
            u2 = c2v + 0.1f * (c2v + s2) * invn;
            float s = u0 + u1 + u2, sq = u0 * u0 + u1 * u1 + u2 * u2;
#pragma unroll
            for (int o = 32; o; o >>= 1) { s += __shfl_xor(s, o); sq += __shfl_xor(sq, o); }
            if (lane == 0) { red[wave] = s; red[4 + wave] = sq; }
        }
        __syncthreads();
        if (tid == 0) {
            red[0] = red[0] + red[1] + red[2] + red[3];
            red[4] = red[4] + red[5] + red[6] + red[7];
        }
        __syncthreads();
        if (tid < 256) {
            float mu   = red[0] / (float)D;
            float var  = red[4] / (float)D - mu * mu;
            float rstd = rsqrtf(var + EPS);
            float* outr = cd + (size_t)(c - 1) * D;
            outr[tid]       = (u0 - mu) * rstd * gamma[tid]       + beta[tid];
            outr[tid + 256] = (u1 - mu) * rstd * gamma[tid + 256] + beta[tid + 256];
            outr[tid + 512] = (u2 - mu) * rstd * gamma[tid + 512] + beta[tid + 512];
        }
    }
}

// ---------------- kC: neg gram + ticket-gated final loss (proven r6-r11) --------
__global__ __launch_bounds__(256) void kC(const float* __restrict__ cd,
        const float* __restrict__ posp, unsigned int* __restrict__ negbits,
        unsigned int* __restrict__ tick, float* __restrict__ out) {
    int i = blockIdx.x;    // 0..94
    int tid = threadIdx.x, wave = tid >> 6, lane = tid & 63;
    __shared__ float rowi[D];
    __shared__ float red[4];
    __shared__ int winner;
    for (int t = tid; t < D; t += 256) rowi[t] = cd[(size_t)i * D + t];
    __syncthreads();
    float acc = 0.f;
    for (int j = wave; j < 95; j += 4) {
        const float* rj = cd + (size_t)j * D;
        float dot = 0.f;
#pragma unroll
        for (int t = 0; t < 12; ++t) dot += rowi[lane + 64 * t] * rj[lane + 64 * t];
#pragma unroll
        for (int o = 32; o; o >>= 1) dot += __shfl_xor(dot, o);
        if (lane == 0) acc += __expf(dot * (1.f / (float)D));
    }
    if (lane == 0) red[wave] = acc;
    __syncthreads();
    if (tid == 0) {
        float val = red[0] + red[1] + red[2] + red[3];
        atomicExch(&negbits[i], __float_as_uint(val));   // device-scope publish
        __threadfence();
        winner = (atomicAdd(&tick[0], 1u) == 94u) ? 1 : 0; // 95th finisher wins
    }
    __syncthreads();
    if (winner && wave == 0) {
        __threadfence();                                 // acquire others' publishes
        double ng = (lane < 95)
            ? (double)__uint_as_float(atomicOr(&negbits[lane], 0u)) : 0.0;
        if (lane < 31)
            ng += (double)__uint_as_float(atomicOr(&negbits[64 + lane], 0u));
        double p = (double)posp[lane];
        if (lane < 32) p += (double)posp[64 + lane];
#pragma unroll
        for (int o = 32; o; o >>= 1) {
            ng += __shfl_xor(ng, o);
            p  += __shfl_xor(p, o);
        }
        if (lane == 0) out[0] = (float)(log(ng) - log(p));
    }
}

extern "C" void kernel_launch(void* const* d_in, const int* in_sizes, int n_in,
                              void* d_out, int out_size, void* d_ws, size_t ws_size,
                              hipStream_t stream) {
    const float* input_f  = (const float*)d_in[0];
    const float* char_dic = (const float*)d_in[1];
    const float* gamma    = (const float*)d_in[2];
    const float* beta     = (const float*)d_in[3];
    const int*   target   = (const int*)d_in[4];
    float* out = (float*)d_out;

    char* ws = (char*)d_ws;
    size_t off = 0;
    auto carve = [&](size_t bytes) -> void* {
        void* p = ws + off;
        off = (off + bytes + 255) & ~(size_t)255;
        return p;
    };
    // +192 pad rows: kB pad-row staging may read past class end (masked in epilogue)
    __hip_bfloat16* xgb = (__hip_bfloat16*)carve((size_t)(NROWS + 192) * D * 2);
    int*          perm    = (int*)  carve((size_t)M * 4);
    int*          counts  = (int*)  carve(NCLS * 4);
    int*          gofs    = (int*)  carve(NCLS * 4);
    float*        posp    = (float*)carve(NCLS * 4);
    float*        cd      = (float*)carve((size_t)95 * D * 4);
    unsigned int* negbits = (unsigned int*)carve(95 * 4);
    unsigned int* tick    = (unsigned int*)carve(64);

    (void)hipFuncSetAttribute((const void*)kB,
            hipFuncAttributeMaxDynamicSharedMemorySize, DYN_B);

    k2_lists<<<NCLS, 256, 0, stream>>>(target, char_dic, perm, counts, gofs, xgb, tick);
    k1_layernorm<<<M / 4, 256, 0, stream>>>(input_f, gamma, beta, perm, xgb);
    kB<<<NCLS + 95, 512, DYN_B, stream>>>(xgb, char_dic, gamma, beta, counts, gofs, posp, cd);
    kC<<<95, 256, 0, stream>>>(cd, posp, negbits, tick, out);
}

// Round 17
// 44.707 us; speedup vs baseline: 1.6583x; 1.1332x over previous
//
#include <hip/hip_runtime.h>
#include <hip/hip_bf16.h>
#include <math.h>

#define D 768
#define NCLS 96
#define M 8192            // 32*256 tokens
#define NROWS (M + NCLS)  // 8288 grouped rows
#define EPS 1e-5f

// gram geometry (proven round-15)
#define KB 384
#define SEGR 48           // KB/8 16B segments per row-chunk
#define MAXR 160          // max rows per class (dict + tokens)
#define DYN_B (MAXR * KB * 2)   // 122880 B dynamic LDS

typedef __attribute__((ext_vector_type(8))) short bf16x8;
typedef __attribute__((ext_vector_type(4))) float f32x4;

// ---------------- K2: counts/gofs/perm + dict copy (round-3 proven) -------------
__global__ __launch_bounds__(256) void k2_lists(const int* __restrict__ labels,
        const float* __restrict__ cdic, int* __restrict__ perm,
        int* __restrict__ counts, int* __restrict__ gofs,
        __hip_bfloat16* __restrict__ xgb, unsigned int* __restrict__ tick) {
    int c = blockIdx.x;
    int tid = threadIdx.x, wave = tid >> 6, lane = tid & 63;
    __shared__ int labs[M];
    __shared__ int ccnt[128];
    __shared__ int cbase[128];
    __shared__ int ltred[4];
    __shared__ int gsh;
    if (c == 0 && tid == 0) tick[0] = 0u;     // reset winner ticket each call
    for (int t = tid; t < M / 4; t += 256)
        ((int4*)labs)[t] = ((const int4*)labels)[t];
    __syncthreads();
    int lt0 = 0;
    for (int ch = wave; ch < 128; ch += 4) {
        int lab = labs[ch * 64 + lane];
        unsigned long long meq = __ballot(lab == c);
        unsigned long long mlt = __ballot(lab < c);
        if (lane == 0) { ccnt[ch] = __popcll(meq); lt0 += __popcll(mlt); }
    }
    if (lane == 0) ltred[wave] = lt0;
    __syncthreads();
    if (wave == 0) {
        int v0 = ccnt[lane], v1 = ccnt[64 + lane];
        int s0 = v0;
#pragma unroll
        for (int o = 1; o < 64; o <<= 1) { int t0 = __shfl_up(s0, o); if (lane >= o) s0 += t0; }
        int tot0 = __shfl(s0, 63);
        int s1 = v1;
#pragma unroll
        for (int o = 1; o < 64; o <<= 1) { int t1 = __shfl_up(s1, o); if (lane >= o) s1 += t1; }
        cbase[lane] = s0 - v0;
        cbase[64 + lane] = tot0 + s1 - v1;
        if (lane == 63) {
            counts[c] = tot0 + s1;
            int g = c + ltred[0] + ltred[1] + ltred[2] + ltred[3];
            gofs[c] = g;
            gsh = g;
        }
    }
    __syncthreads();
    int g = gsh;
    for (int ch = wave; ch < 128; ch += 4) {
        int m = ch * 64 + lane;
        bool match = (labs[m] == c);
        unsigned long long mask = __ballot(match);
        int pre = __popcll(mask & ((1ull << lane) - 1ull));
        if (match) perm[m] = g + 1 + cbase[ch] + pre;
    }
    for (int t = tid; t < D; t += 256)
        xgb[(size_t)g * D + t] = __float2bfloat16(cdic[c * D + t]);
}

// ---------------- K1: LayerNorm + bf16 scatter (round-3 proven) -----------------
__global__ __launch_bounds__(256) void k1_layernorm(const float* __restrict__ x,
        const float* __restrict__ gamma, const float* __restrict__ beta,
        const int* __restrict__ perm, __hip_bfloat16* __restrict__ xgb) {
    int wave = threadIdx.x >> 6;
    int lane = threadIdx.x & 63;
    int row = blockIdx.x * 4 + wave;
    const float* xr = x + (size_t)row * D;
    float4 v[3];
    float s = 0.f, sq = 0.f;
#pragma unroll
    for (int t = 0; t < 3; ++t) {
        v[t] = *(const float4*)(xr + (lane + 64 * t) * 4);
        s  += v[t].x + v[t].y + v[t].z + v[t].w;
        sq += v[t].x * v[t].x + v[t].y * v[t].y + v[t].z * v[t].z + v[t].w * v[t].w;
    }
#pragma unroll
    for (int o = 32; o; o >>= 1) { s += __shfl_xor(s, o); sq += __shfl_xor(sq, o); }
    float mu   = s / (float)D;
    float var  = sq / (float)D - mu * mu;
    float rstd = rsqrtf(var + EPS);
    int dest = perm[row];
    unsigned short* orow = (unsigned short*)xgb + (size_t)dest * D;
#pragma unroll
    for (int t = 0; t < 3; ++t) {
        int base = (lane + 64 * t) * 4;
        float4 g4 = *(const float4*)(gamma + base);
        float4 b4 = *(const float4*)(beta + base);
        float f0 = (v[t].x - mu) * rstd * g4.x + b4.x;
        float f1 = (v[t].y - mu) * rstd * g4.y + b4.y;
        float f2 = (v[t].z - mu) * rstd * g4.z + b4.z;
        float f3 = (v[t].w - mu) * rstd * g4.w + b4.w;
        __hip_bfloat16 h0 = __float2bfloat16(f0), h1 = __float2bfloat16(f1);
        __hip_bfloat16 h2 = __float2bfloat16(f2), h3 = __float2bfloat16(f3);
        ushort4 u;
        u.x = *(unsigned short*)&h0; u.y = *(unsigned short*)&h1;
        u.z = *(unsigned short*)&h2; u.w = *(unsigned short*)&h3;
        *(ushort4*)(orow + base) = u;
    }
}

// ---------------- kB (512 thr): gram (blocks 0..95) || cd (96..190) -------------
// r15 proven body: async global->LDS staging (width 16), linear LDS dest +
// inverse-swizzled per-lane global source; pad-row reads masked in epilogue.
__global__ __launch_bounds__(512) void kB(const __hip_bfloat16* __restrict__ xgbh,
        const float* __restrict__ cdic, const float* __restrict__ gamma,
        const float* __restrict__ beta, const int* __restrict__ counts,
        const int* __restrict__ gofs, float* __restrict__ posp,
        float* __restrict__ cd) {
    int bid = blockIdx.x, tid = threadIdx.x, wave = tid >> 6, lane = tid & 63;

    if (bid < NCLS) {
        // -------- positive gram (r11 8-wave body, async staging) --------
        const unsigned short* xgb = (const unsigned short*)xgbh;
        int c = bid;
        extern __shared__ unsigned short sh[];
        int r0 = gofs[c];
        int nc = counts[c] + 1;
        int ntile = (nc + 31) >> 5;
        int nr = ntile << 5;
        int tott = ntile * (ntile + 1) / 2;
        int s_ti[2], s_tj[2];
#pragma unroll
        for (int slot = 0; slot < 2; ++slot) {
            int t = wave + slot * 8;
            int ti = 0, rem = t, span = ntile;
            if (t < tott) {
                while (rem >= span) { rem -= span; --span; ++ti; }
                s_ti[slot] = ti; s_tj[slot] = ti + rem;
            } else { s_ti[slot] = 0; s_tj[slot] = 0; }
        }
        int r16 = lane & 15, sA = lane >> 4;
        int xr = r16 & 7;
        int e0 = (sA ^ xr) * 8;
        int e1 = ((sA + 4) ^ xr) * 8;
        f32x4 acc[2][4];
#pragma unroll
        for (int s = 0; s < 2; ++s)
#pragma unroll
            for (int q = 0; q < 4; ++q) acc[s][q] = f32x4{0.f, 0.f, 0.f, 0.f};
        for (int kc = 0; kc < D; kc += KB) {
            __syncthreads();
            int totseg = nr * SEGR;          // nr mult of 32 -> totseg mult of 1536
            // async: linear LDS dest (seg q), global src seg (q%48)^(r&7) of row q/48
            for (int qb = wave * 64; qb < totseg; qb += 512) {
                int q = qb + lane;
                int r = q / SEGR, s = q - r * SEGR;
                const unsigned short* src =
                    xgb + (size_t)(r0 + r) * D + kc + ((s ^ (r & 7)) << 3);
                __builtin_amdgcn_global_load_lds(
                    (const __attribute__((address_space(1))) unsigned int*)src,
                    (__attribute__((address_space(3))) unsigned int*)(sh + (size_t)qb * 8),
                    16, 0, 0);
            }
            __syncthreads();
#pragma unroll
            for (int slot = 0; slot < 2; ++slot) {
                if (wave + slot * 8 >= tott) continue;
                int ti = s_ti[slot], tj = s_tj[slot];
                const unsigned short* pa0 = sh + (ti * 32 + r16) * KB;
                const unsigned short* pa1 = pa0 + 16 * KB;
                const unsigned short* pb0 = sh + (tj * 32 + r16) * KB;
                const unsigned short* pb1 = pb0 + 16 * KB;
#pragma unroll
                for (int ks = 0; ks < KB / 32; ++ks) {
                    int ko = (ks >> 1) * 64 + ((ks & 1) ? e1 : e0);
                    bf16x8 a0 = *(const bf16x8*)(pa0 + ko);
                    bf16x8 a1 = *(const bf16x8*)(pa1 + ko);
                    bf16x8 b0 = *(const bf16x8*)(pb0 + ko);
                    bf16x8 b1 = *(const bf16x8*)(pb1 + ko);
                    acc[slot][0] = __builtin_amdgcn_mfma_f32_16x16x32_bf16(a0, b0, acc[slot][0], 0, 0, 0);
                    acc[slot][1] = __builtin_amdgcn_mfma_f32_16x16x32_bf16(a0, b1, acc[slot][1], 0, 0, 0);
                    acc[slot][2] = __builtin_amdgcn_mfma_f32_16x16x32_bf16(a1, b0, acc[slot][2], 0, 0, 0);
                    acc[slot][3] = __builtin_amdgcn_mfma_f32_16x16x32_bf16(a1, b1, acc[slot][3], 0, 0, 0);
                }
            }
        }
        const float inv = 1.f / (float)D;
        float tacc = 0.f;
        int rbase = sA * 4;
#pragma unroll
        for (int slot = 0; slot < 2; ++slot) {
            if (wave + slot * 8 >= tott) continue;
            int ti = s_ti[slot], tj = s_tj[slot];
            float w = (ti == tj) ? 1.f : 2.f;
#pragma unroll
            for (int fa = 0; fa < 2; ++fa)
#pragma unroll
                for (int fb = 0; fb < 2; ++fb)
#pragma unroll
                    for (int reg = 0; reg < 4; ++reg) {
                        int i = ti * 32 + fa * 16 + rbase + reg;
                        int j = tj * 32 + fb * 16 + r16;
                        if (i < nc && j < nc)
                            tacc += w * __expf(acc[slot][fa * 2 + fb][reg] * inv);
                    }
        }
#pragma unroll
        for (int o = 32; o; o >>= 1) tacc += __shfl_xor(tacc, o);
        __syncthreads();
        float* red = (float*)sh;
        if (lane == 0) red[wave] = tacc;
        __syncthreads();
        if (tid == 0)
            posp[c] = ((red[0] + red[1]) + (red[2] + red[3]))
                    + ((red[4] + red[5]) + (red[6] + red[7]));
    } else {
        // -------- cd rows (r11 proven 8-wave body) --------
        int c = bid - 95;            // 1..95
        int n = counts[c];
        const unsigned short* rows = (const unsigned short*)xgbh + (size_t)(gofs[c] + 1) * D;
        float acc[3][4];
#pragma unroll
        for (int p = 0; p < 3; ++p)
#pragma unroll
            for (int e = 0; e < 4; ++e) acc[p][e] = 0.f;
        for (int r = wave; r < n; r += 8) {
            const unsigned short* rp = rows + (size_t)r * D + lane * 4;
#pragma unroll
            for (int p = 0; p < 3; ++p) {
                ushort4 u = *(const ushort4*)(rp + 256 * p);
                acc[p][0] += __bfloat162float(*(const __hip_bfloat16*)&u.x);
                acc[p][1] += __bfloat162float(*(const __hip_bfloat16*)&u.y);
                acc[p][2] += __bfloat162float(*(const __hip_bfloat16*)&u.z);
                acc[p][3] += __bfloat162float(*(const __hip_bfloat16*)&u.w);
            }
        }
        __shared__ float part[8][D];   // 24 KB static
        __shared__ float red[8];
#pragma unroll
        for (int p = 0; p < 3; ++p)
#pragma unroll
            for (int e = 0; e < 4; ++e)
                part[wave][p * 256 + lane * 4 + e] = acc[p][e];
        __syncthreads();
        float u0 = 0.f, u1 = 0.f, u2 = 0.f;
        if (tid < 256) {
            float s0 = 0.f, s1 = 0.f, s2 = 0.f;
#pragma unroll
            for (int w = 0; w < 8; ++w) {
                s0 += part[w][tid];
                s1 += part[w][tid + 256];
                s2 += part[w][tid + 512];
            }
            float invn = 1.f / ((float)n + 1.f);
            float c0 = cdic[c * D + tid], c1 = cdic[c * D + tid + 256], c2v = cdic[c * D + tid + 512];
            u0 = c0 + 0.1f * (c0 + s0) * invn;
            u1 = c1 + 0.1f * (c1 + s1) * invn;
            u2 = c2v + 0.1f * (c2v + s2) * invn;
            float s = u0 + u1 + u2, sq = u0 * u0 + u1 * u1 + u2 * u2;
#pragma unroll
            for (int o = 32; o; o >>= 1) { s += __shfl_xor(s, o); sq += __shfl_xor(sq, o); }
            if (lane == 0) { red[wave] = s; red[4 + wave] = sq; }
        }
        __syncthreads();
        if (tid == 0) {
            red[0] = red[0] + red[1] + red[2] + red[3];
            red[4] = red[4] + red[5] + red[6] + red[7];
        }
        __syncthreads();
        if (tid < 256) {
            float mu   = red[0] / (float)D;
            float var  = red[4] / (float)D - mu * mu;
            float rstd = rsqrtf(var + EPS);
            float* outr = cd + (size_t)(c - 1) * D;
            outr[tid]       = (u0 - mu) * rstd * gamma[tid]       + beta[tid];
            outr[tid + 256] = (u1 - mu) * rstd * gamma[tid + 256] + beta[tid + 256];
            outr[tid + 512] = (u2 - mu) * rstd * gamma[tid + 512] + beta[tid + 512];
        }
    }
}

// ---------------- kC (512 thr): neg gram + ticket-gated final loss --------------
__global__ __launch_bounds__(512) void kC(const float* __restrict__ cd,
        const float* __restrict__ posp, unsigned int* __restrict__ negbits,
        unsigned int* __restrict__ tick, float* __restrict__ out) {
    int i = blockIdx.x;    // 0..94
    int tid = threadIdx.x, wave = tid >> 6, lane = tid & 63;
    __shared__ float rowi[D];
    __shared__ float red[8];
    __shared__ int winner;
    for (int t = tid; t < D; t += 512) rowi[t] = cd[(size_t)i * D + t];
    __syncthreads();
    float acc = 0.f;
    for (int j = wave; j < 95; j += 8) {
        const float* rj = cd + (size_t)j * D;
        float dot = 0.f;
#pragma unroll
        for (int t = 0; t < 12; ++t) dot += rowi[lane + 64 * t] * rj[lane + 64 * t];
#pragma unroll
        for (int o = 32; o; o >>= 1) dot += __shfl_xor(dot, o);
        if (lane == 0) acc += __expf(dot * (1.f / (float)D));
    }
    if (lane == 0) red[wave] = acc;
    __syncthreads();
    if (tid == 0) {
        float val = ((red[0] + red[1]) + (red[2] + red[3]))
                  + ((red[4] + red[5]) + (red[6] + red[7]));
        atomicExch(&negbits[i], __float_as_uint(val));   // device-scope publish
        __threadfence();
        winner = (atomicAdd(&tick[0], 1u) == 94u) ? 1 : 0; // 95th finisher wins
    }
    __syncthreads();
    if (winner && wave == 0) {
        __threadfence();                                 // acquire others' publishes
        double ng = (lane < 95)
            ? (double)__uint_as_float(atomicOr(&negbits[lane], 0u)) : 0.0;
        if (lane < 31)
            ng += (double)__uint_as_float(atomicOr(&negbits[64 + lane], 0u));
        double p = (double)posp[lane];
        if (lane < 32) p += (double)posp[64 + lane];
#pragma unroll
        for (int o = 32; o; o >>= 1) {
            ng += __shfl_xor(ng, o);
            p  += __shfl_xor(p, o);
        }
        if (lane == 0) out[0] = (float)(log(ng) - log(p));
    }
}

extern "C" void kernel_launch(void* const* d_in, const int* in_sizes, int n_in,
                              void* d_out, int out_size, void* d_ws, size_t ws_size,
                              hipStream_t stream) {
    const float* input_f  = (const float*)d_in[0];
    const float* char_dic = (const float*)d_in[1];
    const float* gamma    = (const float*)d_in[2];
    const float* beta     = (const float*)d_in[3];
    const int*   target   = (const int*)d_in[4];
    float* out = (float*)d_out;

    char* ws = (char*)d_ws;
    size_t off = 0;
    auto carve = [&](size_t bytes) -> void* {
        void* p = ws + off;
        off = (off + bytes + 255) & ~(size_t)255;
        return p;
    };
    // +192 pad rows: kB pad-row staging may read past class end (masked in epilogue)
    __hip_bfloat16* xgb = (__hip_bfloat16*)carve((size_t)(NROWS + 192) * D * 2);
    int*          perm    = (int*)  carve((size_t)M * 4);
    int*          counts  = (int*)  carve(NCLS * 4);
    int*          gofs    = (int*)  carve(NCLS * 4);
    float*        posp    = (float*)carve(NCLS * 4);
    float*        cd      = (float*)carve((size_t)95 * D * 4);
    unsigned int* negbits = (unsigned int*)carve(95 * 4);
    unsigned int* tick    = (unsigned int*)carve(64);

    (void)hipFuncSetAttribute((const void*)kB,
            hipFuncAttributeMaxDynamicSharedMemorySize, DYN_B);

    k2_lists<<<NCLS, 256, 0, stream>>>(target, char_dic, perm, counts, gofs, xgb, tick);
    k1_layernorm<<<M / 4, 256, 0, stream>>>(input_f, gamma, beta, perm, xgb);
    kB<<<NCLS + 95, 512, DYN_B, stream>>>(xgb, char_dic, gamma, beta, counts, gofs, posp, cd);
    kC<<<95, 512, 0, stream>>>(cd, posp, negbits, tick, out);
}

// Round 18
// 41.654 us; speedup vs baseline: 1.7798x; 1.0733x over previous
//
#include <hip/hip_runtime.h>
#include <hip/hip_bf16.h>
#include <math.h>

#define D 768
#define NCLS 96
#define M 8192            // 32*256 tokens
#define NROWS (M + NCLS)  // 8288 grouped rows
#define EPS 1e-5f

// gram geometry (proven round-15)
#define KB 384
#define SEGR 48           // KB/8 16B segments per row-chunk
#define MAXR 160          // max rows per class (dict + tokens)
#define DYN_B (MAXR * KB * 2)   // 122880 B dynamic LDS

typedef __attribute__((ext_vector_type(8))) short bf16x8;
typedef __attribute__((ext_vector_type(4))) float f32x4;

// ---------------- K2 (512 thr): counts/gofs/perm + dict copy --------------------
__global__ __launch_bounds__(512) void k2_lists(const int* __restrict__ labels,
        const float* __restrict__ cdic, int* __restrict__ perm,
        int* __restrict__ counts, int* __restrict__ gofs,
        __hip_bfloat16* __restrict__ xgb, unsigned int* __restrict__ tick) {
    int c = blockIdx.x;
    int tid = threadIdx.x, wave = tid >> 6, lane = tid & 63;
    __shared__ int labs[M];
    __shared__ int ccnt[128];
    __shared__ int cbase[128];
    __shared__ int ltred[8];
    __shared__ int gsh;
    if (c == 0 && tid == 0) tick[0] = 0u;     // reset winner ticket each call
    for (int t = tid; t < M / 4; t += 512)
        ((int4*)labs)[t] = ((const int4*)labels)[t];
    __syncthreads();
    int lt0 = 0;
    for (int ch = wave; ch < 128; ch += 8) {
        int lab = labs[ch * 64 + lane];
        unsigned long long meq = __ballot(lab == c);
        unsigned long long mlt = __ballot(lab < c);
        if (lane == 0) { ccnt[ch] = __popcll(meq); lt0 += __popcll(mlt); }
    }
    if (lane == 0) ltred[wave] = lt0;
    __syncthreads();
    if (wave == 0) {
        int v0 = ccnt[lane], v1 = ccnt[64 + lane];
        int s0 = v0;
#pragma unroll
        for (int o = 1; o < 64; o <<= 1) { int t0 = __shfl_up(s0, o); if (lane >= o) s0 += t0; }
        int tot0 = __shfl(s0, 63);
        int s1 = v1;
#pragma unroll
        for (int o = 1; o < 64; o <<= 1) { int t1 = __shfl_up(s1, o); if (lane >= o) s1 += t1; }
        cbase[lane] = s0 - v0;
        cbase[64 + lane] = tot0 + s1 - v1;
        if (lane == 63) {
            counts[c] = tot0 + s1;
            int g = c + ((ltred[0] + ltred[1]) + (ltred[2] + ltred[3]))
                      + ((ltred[4] + ltred[5]) + (ltred[6] + ltred[7]));
            gofs[c] = g;
            gsh = g;
        }
    }
    __syncthreads();
    int g = gsh;
    for (int ch = wave; ch < 128; ch += 8) {
        int m = ch * 64 + lane;
        bool match = (labs[m] == c);
        unsigned long long mask = __ballot(match);
        int pre = __popcll(mask & ((1ull << lane) - 1ull));
        if (match) perm[m] = g + 1 + cbase[ch] + pre;
    }
    for (int t = tid; t < D; t += 512)
        xgb[(size_t)g * D + t] = __float2bfloat16(cdic[c * D + t]);
}

// ---------------- K1: LayerNorm + bf16 scatter (round-3 proven) -----------------
__global__ __launch_bounds__(256) void k1_layernorm(const float* __restrict__ x,
        const float* __restrict__ gamma, const float* __restrict__ beta,
        const int* __restrict__ perm, __hip_bfloat16* __restrict__ xgb) {
    int wave = threadIdx.x >> 6;
    int lane = threadIdx.x & 63;
    int row = blockIdx.x * 4 + wave;
    const float* xr = x + (size_t)row * D;
    float4 v[3];
    float s = 0.f, sq = 0.f;
#pragma unroll
    for (int t = 0; t < 3; ++t) {
        v[t] = *(const float4*)(xr + (lane + 64 * t) * 4);
        s  += v[t].x + v[t].y + v[t].z + v[t].w;
        sq += v[t].x * v[t].x + v[t].y * v[t].y + v[t].z * v[t].z + v[t].w * v[t].w;
    }
#pragma unroll
    for (int o = 32; o; o >>= 1) { s += __shfl_xor(s, o); sq += __shfl_xor(sq, o); }
    float mu   = s / (float)D;
    float var  = sq / (float)D - mu * mu;
    float rstd = rsqrtf(var + EPS);
    int dest = perm[row];
    unsigned short* orow = (unsigned short*)xgb + (size_t)dest * D;
#pragma unroll
    for (int t = 0; t < 3; ++t) {
        int base = (lane + 64 * t) * 4;
        float4 g4 = *(const float4*)(gamma + base);
        float4 b4 = *(const float4*)(beta + base);
        float f0 = (v[t].x - mu) * rstd * g4.x + b4.x;
        float f1 = (v[t].y - mu) * rstd * g4.y + b4.y;
        float f2 = (v[t].z - mu) * rstd * g4.z + b4.z;
        float f3 = (v[t].w - mu) * rstd * g4.w + b4.w;
        __hip_bfloat16 h0 = __float2bfloat16(f0), h1 = __float2bfloat16(f1);
        __hip_bfloat16 h2 = __float2bfloat16(f2), h3 = __float2bfloat16(f3);
        ushort4 u;
        u.x = *(unsigned short*)&h0; u.y = *(unsigned short*)&h1;
        u.z = *(unsigned short*)&h2; u.w = *(unsigned short*)&h3;
        *(ushort4*)(orow + base) = u;
    }
}

// ---------------- kB (512 thr): gram (blocks 0..95) || cd (96..190) -------------
// r15 proven body: async global->LDS staging (width 16), linear LDS dest +
// inverse-swizzled per-lane global source; pad-row reads masked in epilogue.
__global__ __launch_bounds__(512) void kB(const __hip_bfloat16* __restrict__ xgbh,
        const float* __restrict__ cdic, const float* __restrict__ gamma,
        const float* __restrict__ beta, const int* __restrict__ counts,
        const int* __restrict__ gofs, float* __restrict__ posp,
        float* __restrict__ cd) {
    int bid = blockIdx.x, tid = threadIdx.x, wave = tid >> 6, lane = tid & 63;

    if (bid < NCLS) {
        // -------- positive gram (r11 8-wave body, async staging) --------
        const unsigned short* xgb = (const unsigned short*)xgbh;
        int c = bid;
        extern __shared__ unsigned short sh[];
        int r0 = gofs[c];
        int nc = counts[c] + 1;
        int ntile = (nc + 31) >> 5;
        int nr = ntile << 5;
        int tott = ntile * (ntile + 1) / 2;
        int s_ti[2], s_tj[2];
#pragma unroll
        for (int slot = 0; slot < 2; ++slot) {
            int t = wave + slot * 8;
            int ti = 0, rem = t, span = ntile;
            if (t < tott) {
                while (rem >= span) { rem -= span; --span; ++ti; }
                s_ti[slot] = ti; s_tj[slot] = ti + rem;
            } else { s_ti[slot] = 0; s_tj[slot] = 0; }
        }
        int r16 = lane & 15, sA = lane >> 4;
        int xr = r16 & 7;
        int e0 = (sA ^ xr) * 8;
        int e1 = ((sA + 4) ^ xr) * 8;
        f32x4 acc[2][4];
#pragma unroll
        for (int s = 0; s < 2; ++s)
#pragma unroll
            for (int q = 0; q < 4; ++q) acc[s][q] = f32x4{0.f, 0.f, 0.f, 0.f};
        for (int kc = 0; kc < D; kc += KB) {
            __syncthreads();
            int totseg = nr * SEGR;          // nr mult of 32 -> totseg mult of 1536
            // async: linear LDS dest (seg q), global src seg (q%48)^(r&7) of row q/48
            for (int qb = wave * 64; qb < totseg; qb += 512) {
                int q = qb + lane;
                int r = q / SEGR, s = q - r * SEGR;
                const unsigned short* src =
                    xgb + (size_t)(r0 + r) * D + kc + ((s ^ (r & 7)) << 3);
                __builtin_amdgcn_global_load_lds(
                    (const __attribute__((address_space(1))) unsigned int*)src,
                    (__attribute__((address_space(3))) unsigned int*)(sh + (size_t)qb * 8),
                    16, 0, 0);
            }
            __syncthreads();
#pragma unroll
            for (int slot = 0; slot < 2; ++slot) {
                if (wave + slot * 8 >= tott) continue;
                int ti = s_ti[slot], tj = s_tj[slot];
                const unsigned short* pa0 = sh + (ti * 32 + r16) * KB;
                const unsigned short* pa1 = pa0 + 16 * KB;
                const unsigned short* pb0 = sh + (tj * 32 + r16) * KB;
                const unsigned short* pb1 = pb0 + 16 * KB;
#pragma unroll
                for (int ks = 0; ks < KB / 32; ++ks) {
                    int ko = (ks >> 1) * 64 + ((ks & 1) ? e1 : e0);
                    bf16x8 a0 = *(const bf16x8*)(pa0 + ko);
                    bf16x8 a1 = *(const bf16x8*)(pa1 + ko);
                    bf16x8 b0 = *(const bf16x8*)(pb0 + ko);
                    bf16x8 b1 = *(const bf16x8*)(pb1 + ko);
                    acc[slot][0] = __builtin_amdgcn_mfma_f32_16x16x32_bf16(a0, b0, acc[slot][0], 0, 0, 0);
                    acc[slot][1] = __builtin_amdgcn_mfma_f32_16x16x32_bf16(a0, b1, acc[slot][1], 0, 0, 0);
                    acc[slot][2] = __builtin_amdgcn_mfma_f32_16x16x32_bf16(a1, b0, acc[slot][2], 0, 0, 0);
                    acc[slot][3] = __builtin_amdgcn_mfma_f32_16x16x32_bf16(a1, b1, acc[slot][3], 0, 0, 0);
                }
            }
        }
        const float inv = 1.f / (float)D;
        float tacc = 0.f;
        int rbase = sA * 4;
#pragma unroll
        for (int slot = 0; slot < 2; ++slot) {
            if (wave + slot * 8 >= tott) continue;
            int ti = s_ti[slot], tj = s_tj[slot];
            float w = (ti == tj) ? 1.f : 2.f;
#pragma unroll
            for (int fa = 0; fa < 2; ++fa)
#pragma unroll
                for (int fb = 0; fb < 2; ++fb)
#pragma unroll
                    for (int reg = 0; reg < 4; ++reg) {
                        int i = ti * 32 + fa * 16 + rbase + reg;
                        int j = tj * 32 + fb * 16 + r16;
                        if (i < nc && j < nc)
                            tacc += w * __expf(acc[slot][fa * 2 + fb][reg] * inv);
                    }
        }
#pragma unroll
        for (int o = 32; o; o >>= 1) tacc += __shfl_xor(tacc, o);
        __syncthreads();
        float* red = (float*)sh;
        if (lane == 0) red[wave] = tacc;
        __syncthreads();
        if (tid == 0)
            posp[c] = ((red[0] + red[1]) + (red[2] + red[3]))
                    + ((red[4] + red[5]) + (red[6] + red[7]));
    } else {
        // -------- cd rows (r11 proven 8-wave body) --------
        int c = bid - 95;            // 1..95
        int n = counts[c];
        const unsigned short* rows = (const unsigned short*)xgbh + (size_t)(gofs[c] + 1) * D;
        float acc[3][4];
#pragma unroll
        for (int p = 0; p < 3; ++p)
#pragma unroll
            for (int e = 0; e < 4; ++e) acc[p][e] = 0.f;
        for (int r = wave; r < n; r += 8) {
            const unsigned short* rp = rows + (size_t)r * D + lane * 4;
#pragma unroll
            for (int p = 0; p < 3; ++p) {
                ushort4 u = *(const ushort4*)(rp + 256 * p);
                acc[p][0] += __bfloat162float(*(const __hip_bfloat16*)&u.x);
                acc[p][1] += __bfloat162float(*(const __hip_bfloat16*)&u.y);
                acc[p][2] += __bfloat162float(*(const __hip_bfloat16*)&u.z);
                acc[p][3] += __bfloat162float(*(const __hip_bfloat16*)&u.w);
            }
        }
        __shared__ float part[8][D];   // 24 KB static
        __shared__ float red[8];
#pragma unroll
        for (int p = 0; p < 3; ++p)
#pragma unroll
            for (int e = 0; e < 4; ++e)
                part[wave][p * 256 + lane * 4 + e] = acc[p][e];
        __syncthreads();
        float u0 = 0.f, u1 = 0.f, u2 = 0.f;
        if (tid < 256) {
            float s0 = 0.f, s1 = 0.f, s2 = 0.f;
#pragma unroll
            for (int w = 0; w < 8; ++w) {
                s0 += part[w][tid];
                s1 += part[w][tid + 256];
                s2 += part[w][tid + 512];
            }
            float invn = 1.f / ((float)n + 1.f);
            float c0 = cdic[c * D + tid], c1 = cdic[c * D + tid + 256], c2v = cdic[c * D + tid + 512];
            u0 = c0 + 0.1f * (c0 + s0) * invn;
            u1 = c1 + 0.1f * (c1 + s1) * invn;
            u2 = c2v + 0.1f * (c2v + s2) * invn;
            float s = u0 + u1 + u2, sq = u0 * u0 + u1 * u1 + u2 * u2;
#pragma unroll
            for (int o = 32; o; o >>= 1) { s += __shfl_xor(s, o); sq += __shfl_xor(sq, o); }
            if (lane == 0) { red[wave] = s; red[4 + wave] = sq; }
        }
        __syncthreads();
        if (tid == 0) {
            red[0] = red[0] + red[1] + red[2] + red[3];
            red[4] = red[4] + red[5] + red[6] + red[7];
        }
        __syncthreads();
        if (tid < 256) {
            float mu   = red[0] / (float)D;
            float var  = red[4] / (float)D - mu * mu;
            float rstd = rsqrtf(var + EPS);
            float* outr = cd + (size_t)(c - 1) * D;
            outr[tid]       = (u0 - mu) * rstd * gamma[tid]       + beta[tid];
            outr[tid + 256] = (u1 - mu) * rstd * gamma[tid + 256] + beta[tid + 256];
            outr[tid + 512] = (u2 - mu) * rstd * gamma[tid + 512] + beta[tid + 512];
        }
    }
}

// ---------------- kC (512 thr): neg gram + ticket-gated final loss --------------
__global__ __launch_bounds__(512) void kC(const float* __restrict__ cd,
        const float* __restrict__ posp, unsigned int* __restrict__ negbits,
        unsigned int* __restrict__ tick, float* __restrict__ out) {
    int i = blockIdx.x;    // 0..94
    int tid = threadIdx.x, wave = tid >> 6, lane = tid & 63;
    __shared__ float rowi[D];
    __shared__ float red[8];
    __shared__ int winner;
    for (int t = tid; t < D; t += 512) rowi[t] = cd[(size_t)i * D + t];
    __syncthreads();
    float acc = 0.f;
    for (int j = wave; j < 95; j += 8) {
        const float* rj = cd + (size_t)j * D;
        float dot = 0.f;
#pragma unroll
        for (int t = 0; t < 12; ++t) dot += rowi[lane + 64 * t] * rj[lane + 64 * t];
#pragma unroll
        for (int o = 32; o; o >>= 1) dot += __shfl_xor(dot, o);
        if (lane == 0) acc += __expf(dot * (1.f / (float)D));
    }
    if (lane == 0) red[wave] = acc;
    __syncthreads();
    if (tid == 0) {
        float val = ((red[0] + red[1]) + (red[2] + red[3]))
                  + ((red[4] + red[5]) + (red[6] + red[7]));
        atomicExch(&negbits[i], __float_as_uint(val));   // device-scope publish
        __threadfence();
        winner = (atomicAdd(&tick[0], 1u) == 94u) ? 1 : 0; // 95th finisher wins
    }
    __syncthreads();
    if (winner && wave == 0) {
        __threadfence();                                 // acquire others' publishes
        double ng = (lane < 95)
            ? (double)__uint_as_float(atomicOr(&negbits[lane], 0u)) : 0.0;
        if (lane < 31)
            ng += (double)__uint_as_float(atomicOr(&negbits[64 + lane], 0u));
        double p = (double)posp[lane];
        if (lane < 32) p += (double)posp[64 + lane];
#pragma unroll
        for (int o = 32; o; o >>= 1) {
            ng += __shfl_xor(ng, o);
            p  += __shfl_xor(p, o);
        }
        if (lane == 0) out[0] = (float)(log(ng) - log(p));
    }
}

extern "C" void kernel_launch(void* const* d_in, const int* in_sizes, int n_in,
                              void* d_out, int out_size, void* d_ws, size_t ws_size,
                              hipStream_t stream) {
    const float* input_f  = (const float*)d_in[0];
    const float* char_dic = (const float*)d_in[1];
    const float* gamma    = (const float*)d_in[2];
    const float* beta     = (const float*)d_in[3];
    const int*   target   = (const int*)d_in[4];
    float* out = (float*)d_out;

    char* ws = (char*)d_ws;
    size_t off = 0;
    auto carve = [&](size_t bytes) -> void* {
        void* p = ws + off;
        off = (off + bytes + 255) & ~(size_t)255;
        return p;
    };
    // +192 pad rows: kB pad-row staging may read past class end (masked in epilogue)
    __hip_bfloat16* xgb = (__hip_bfloat16*)carve((size_t)(NROWS + 192) * D * 2);
    int*          perm    = (int*)  carve((size_t)M * 4);
    int*          counts  = (int*)  carve(NCLS * 4);
    int*          gofs    = (int*)  carve(NCLS * 4);
    float*        posp    = (float*)carve(NCLS * 4);
    float*        cd      = (float*)carve((size_t)95 * D * 4);
    unsigned int* negbits = (unsigned int*)carve(95 * 4);
    unsigned int* tick    = (unsigned int*)carve(64);

    (void)hipFuncSetAttribute((const void*)kB,
            hipFuncAttributeMaxDynamicSharedMemorySize, DYN_B);

    k2_lists<<<NCLS, 512, 0, stream>>>(target, char_dic, perm, counts, gofs, xgb, tick);
    k1_layernorm<<<M / 4, 256, 0, stream>>>(input_f, gamma, beta, perm, xgb);
    kB<<<NCLS + 95, 512, DYN_B, stream>>>(xgb, char_dic, gamma, beta, counts, gofs, posp, cd);
    kC<<<95, 512, 0, stream>>>(cd, posp, negbits, tick, out);
}

// Round 19
// 41.505 us; speedup vs baseline: 1.7862x; 1.0036x over previous
//
#include <hip/hip_runtime.h>
#include <hip/hip_bf16.h>
#include <math.h>

#define D 768
#define NCLS 96
#define M 8192            // 32*256 tokens
#define NROWS (M + NCLS)  // 8288 grouped rows
#define EPS 1e-5f

// gram geometry (proven round-15)
#define KB 384
#define SEGR 48           // KB/8 16B segments per row-chunk
#define MAXR 160          // max rows per class (dict + tokens)
#define DYN_B (MAXR * KB * 2)   // 122880 B dynamic LDS

typedef __attribute__((ext_vector_type(8))) short bf16x8;
typedef __attribute__((ext_vector_type(4))) float f32x4;

// ---------------- K2 (512 thr): counts/gofs/perm + dict copy --------------------
__global__ __launch_bounds__(512) void k2_lists(const int* __restrict__ labels,
        const float* __restrict__ cdic, int* __restrict__ perm,
        int* __restrict__ counts, int* __restrict__ gofs,
        __hip_bfloat16* __restrict__ xgb, unsigned int* __restrict__ tick) {
    int c = blockIdx.x;
    int tid = threadIdx.x, wave = tid >> 6, lane = tid & 63;
    __shared__ int labs[M];
    __shared__ int ccnt[128];
    __shared__ int cbase[128];
    __shared__ int ltred[8];
    __shared__ int gsh;
    if (c == 0 && tid == 0) tick[0] = 0u;     // reset winner ticket each call
    for (int t = tid; t < M / 4; t += 512)
        ((int4*)labs)[t] = ((const int4*)labels)[t];
    __syncthreads();
    int lt0 = 0;
    for (int ch = wave; ch < 128; ch += 8) {
        int lab = labs[ch * 64 + lane];
        unsigned long long meq = __ballot(lab == c);
        unsigned long long mlt = __ballot(lab < c);
        if (lane == 0) { ccnt[ch] = __popcll(meq); lt0 += __popcll(mlt); }
    }
    if (lane == 0) ltred[wave] = lt0;
    __syncthreads();
    if (wave == 0) {
        int v0 = ccnt[lane], v1 = ccnt[64 + lane];
        int s0 = v0;
#pragma unroll
        for (int o = 1; o < 64; o <<= 1) { int t0 = __shfl_up(s0, o); if (lane >= o) s0 += t0; }
        int tot0 = __shfl(s0, 63);
        int s1 = v1;
#pragma unroll
        for (int o = 1; o < 64; o <<= 1) { int t1 = __shfl_up(s1, o); if (lane >= o) s1 += t1; }
        cbase[lane] = s0 - v0;
        cbase[64 + lane] = tot0 + s1 - v1;
        if (lane == 63) {
            counts[c] = tot0 + s1;
            int g = c + ((ltred[0] + ltred[1]) + (ltred[2] + ltred[3]))
                      + ((ltred[4] + ltred[5]) + (ltred[6] + ltred[7]));
            gofs[c] = g;
            gsh = g;
        }
    }
    __syncthreads();
    int g = gsh;
    for (int ch = wave; ch < 128; ch += 8) {
        int m = ch * 64 + lane;
        bool match = (labs[m] == c);
        unsigned long long mask = __ballot(match);
        int pre = __popcll(mask & ((1ull << lane) - 1ull));
        if (match) perm[m] = g + 1 + cbase[ch] + pre;
    }
    for (int t = tid; t < D; t += 512)
        xgb[(size_t)g * D + t] = __float2bfloat16(cdic[c * D + t]);
}

// ---------------- K1: LayerNorm + bf16 scatter (round-3 proven) -----------------
__global__ __launch_bounds__(256) void k1_layernorm(const float* __restrict__ x,
        const float* __restrict__ gamma, const float* __restrict__ beta,
        const int* __restrict__ perm, __hip_bfloat16* __restrict__ xgb) {
    int wave = threadIdx.x >> 6;
    int lane = threadIdx.x & 63;
    int row = blockIdx.x * 4 + wave;
    const float* xr = x + (size_t)row * D;
    float4 v[3];
    float s = 0.f, sq = 0.f;
#pragma unroll
    for (int t = 0; t < 3; ++t) {
        v[t] = *(const float4*)(xr + (lane + 64 * t) * 4);
        s  += v[t].x + v[t].y + v[t].z + v[t].w;
        sq += v[t].x * v[t].x + v[t].y * v[t].y + v[t].z * v[t].z + v[t].w * v[t].w;
    }
#pragma unroll
    for (int o = 32; o; o >>= 1) { s += __shfl_xor(s, o); sq += __shfl_xor(sq, o); }
    float mu   = s / (float)D;
    float var  = sq / (float)D - mu * mu;
    float rstd = rsqrtf(var + EPS);
    int dest = perm[row];
    unsigned short* orow = (unsigned short*)xgb + (size_t)dest * D;
#pragma unroll
    for (int t = 0; t < 3; ++t) {
        int base = (lane + 64 * t) * 4;
        float4 g4 = *(const float4*)(gamma + base);
        float4 b4 = *(const float4*)(beta + base);
        float f0 = (v[t].x - mu) * rstd * g4.x + b4.x;
        float f1 = (v[t].y - mu) * rstd * g4.y + b4.y;
        float f2 = (v[t].z - mu) * rstd * g4.z + b4.z;
        float f3 = (v[t].w - mu) * rstd * g4.w + b4.w;
        __hip_bfloat16 h0 = __float2bfloat16(f0), h1 = __float2bfloat16(f1);
        __hip_bfloat16 h2 = __float2bfloat16(f2), h3 = __float2bfloat16(f3);
        ushort4 u;
        u.x = *(unsigned short*)&h0; u.y = *(unsigned short*)&h1;
        u.z = *(unsigned short*)&h2; u.w = *(unsigned short*)&h3;
        *(ushort4*)(orow + base) = u;
    }
}

// ---------------- kB (512 thr): gram (blocks 0..95) || cd (96..190) -------------
// r15 proven body + trimmed staging: stage only ceil512(nc*SEGR) segments
// (pad-tile rows stay unwritten garbage; their accumulator entries are masked
// before exp, and MFMA output entries are row-independent -> safe).
__global__ __launch_bounds__(512) void kB(const __hip_bfloat16* __restrict__ xgbh,
        const float* __restrict__ cdic, const float* __restrict__ gamma,
        const float* __restrict__ beta, const int* __restrict__ counts,
        const int* __restrict__ gofs, float* __restrict__ posp,
        float* __restrict__ cd) {
    int bid = blockIdx.x, tid = threadIdx.x, wave = tid >> 6, lane = tid & 63;

    if (bid < NCLS) {
        // -------- positive gram (r11 8-wave body, async staging) --------
        const unsigned short* xgb = (const unsigned short*)xgbh;
        int c = bid;
        extern __shared__ unsigned short sh[];
        int r0 = gofs[c];
        int nc = counts[c] + 1;
        int ntile = (nc + 31) >> 5;
        int tott = ntile * (ntile + 1) / 2;
        int s_ti[2], s_tj[2];
#pragma unroll
        for (int slot = 0; slot < 2; ++slot) {
            int t = wave + slot * 8;
            int ti = 0, rem = t, span = ntile;
            if (t < tott) {
                while (rem >= span) { rem -= span; --span; ++ti; }
                s_ti[slot] = ti; s_tj[slot] = ti + rem;
            } else { s_ti[slot] = 0; s_tj[slot] = 0; }
        }
        int r16 = lane & 15, sA = lane >> 4;
        int xr = r16 & 7;
        int e0 = (sA ^ xr) * 8;
        int e1 = ((sA + 4) ^ xr) * 8;
        f32x4 acc[2][4];
#pragma unroll
        for (int s = 0; s < 2; ++s)
#pragma unroll
            for (int q = 0; q < 4; ++q) acc[s][q] = f32x4{0.f, 0.f, 0.f, 0.f};
        // trimmed: only real rows (rounded up to full 512-seg waves; <= MAXR*SEGR)
        int totseg = (nc * SEGR + 511) & ~511;
        for (int kc = 0; kc < D; kc += KB) {
            __syncthreads();
            // async: linear LDS dest (seg q), global src seg (q%48)^(r&7) of row q/48
            for (int qb = wave * 64; qb < totseg; qb += 512) {
                int q = qb + lane;
                int r = q / SEGR, s = q - r * SEGR;
                const unsigned short* src =
                    xgb + (size_t)(r0 + r) * D + kc + ((s ^ (r & 7)) << 3);
                __builtin_amdgcn_global_load_lds(
                    (const __attribute__((address_space(1))) unsigned int*)src,
                    (__attribute__((address_space(3))) unsigned int*)(sh + (size_t)qb * 8),
                    16, 0, 0);
            }
            __syncthreads();
#pragma unroll
            for (int slot = 0; slot < 2; ++slot) {
                if (wave + slot * 8 >= tott) continue;
                int ti = s_ti[slot], tj = s_tj[slot];
                const unsigned short* pa0 = sh + (ti * 32 + r16) * KB;
                const unsigned short* pa1 = pa0 + 16 * KB;
                const unsigned short* pb0 = sh + (tj * 32 + r16) * KB;
                const unsigned short* pb1 = pb0 + 16 * KB;
#pragma unroll
                for (int ks = 0; ks < KB / 32; ++ks) {
                    int ko = (ks >> 1) * 64 + ((ks & 1) ? e1 : e0);
                    bf16x8 a0 = *(const bf16x8*)(pa0 + ko);
                    bf16x8 a1 = *(const bf16x8*)(pa1 + ko);
                    bf16x8 b0 = *(const bf16x8*)(pb0 + ko);
                    bf16x8 b1 = *(const bf16x8*)(pb1 + ko);
                    acc[slot][0] = __builtin_amdgcn_mfma_f32_16x16x32_bf16(a0, b0, acc[slot][0], 0, 0, 0);
                    acc[slot][1] = __builtin_amdgcn_mfma_f32_16x16x32_bf16(a0, b1, acc[slot][1], 0, 0, 0);
                    acc[slot][2] = __builtin_amdgcn_mfma_f32_16x16x32_bf16(a1, b0, acc[slot][2], 0, 0, 0);
                    acc[slot][3] = __builtin_amdgcn_mfma_f32_16x16x32_bf16(a1, b1, acc[slot][3], 0, 0, 0);
                }
            }
        }
        const float inv = 1.f / (float)D;
        float tacc = 0.f;
        int rbase = sA * 4;
#pragma unroll
        for (int slot = 0; slot < 2; ++slot) {
            if (wave + slot * 8 >= tott) continue;
            int ti = s_ti[slot], tj = s_tj[slot];
            float w = (ti == tj) ? 1.f : 2.f;
#pragma unroll
            for (int fa = 0; fa < 2; ++fa)
#pragma unroll
                for (int fb = 0; fb < 2; ++fb)
#pragma unroll
                    for (int reg = 0; reg < 4; ++reg) {
                        int i = ti * 32 + fa * 16 + rbase + reg;
                        int j = tj * 32 + fb * 16 + r16;
                        if (i < nc && j < nc)
                            tacc += w * __expf(acc[slot][fa * 2 + fb][reg] * inv);
                    }
        }
#pragma unroll
        for (int o = 32; o; o >>= 1) tacc += __shfl_xor(tacc, o);
        __syncthreads();
        float* red = (float*)sh;
        if (lane == 0) red[wave] = tacc;
        __syncthreads();
        if (tid == 0)
            posp[c] = ((red[0] + red[1]) + (red[2] + red[3]))
                    + ((red[4] + red[5]) + (red[6] + red[7]));
    } else {
        // -------- cd rows (r11 proven 8-wave body) --------
        int c = bid - 95;            // 1..95
        int n = counts[c];
        const unsigned short* rows = (const unsigned short*)xgbh + (size_t)(gofs[c] + 1) * D;
        float acc[3][4];
#pragma unroll
        for (int p = 0; p < 3; ++p)
#pragma unroll
            for (int e = 0; e < 4; ++e) acc[p][e] = 0.f;
        for (int r = wave; r < n; r += 8) {
            const unsigned short* rp = rows + (size_t)r * D + lane * 4;
#pragma unroll
            for (int p = 0; p < 3; ++p) {
                ushort4 u = *(const ushort4*)(rp + 256 * p);
                acc[p][0] += __bfloat162float(*(const __hip_bfloat16*)&u.x);
                acc[p][1] += __bfloat162float(*(const __hip_bfloat16*)&u.y);
                acc[p][2] += __bfloat162float(*(const __hip_bfloat16*)&u.z);
                acc[p][3] += __bfloat162float(*(const __hip_bfloat16*)&u.w);
            }
        }
        __shared__ float part[8][D];   // 24 KB static
        __shared__ float red[8];
#pragma unroll
        for (int p = 0; p < 3; ++p)
#pragma unroll
            for (int e = 0; e < 4; ++e)
                part[wave][p * 256 + lane * 4 + e] = acc[p][e];
        __syncthreads();
        float u0 = 0.f, u1 = 0.f, u2 = 0.f;
        if (tid < 256) {
            float s0 = 0.f, s1 = 0.f, s2 = 0.f;
#pragma unroll
            for (int w = 0; w < 8; ++w) {
                s0 += part[w][tid];
                s1 += part[w][tid + 256];
                s2 += part[w][tid + 512];
            }
            float invn = 1.f / ((float)n + 1.f);
            float c0 = cdic[c * D + tid], c1 = cdic[c * D + tid + 256], c2v = cdic[c * D + tid + 512];
            u0 = c0 + 0.1f * (c0 + s0) * invn;
            u1 = c1 + 0.1f * (c1 + s1) * invn;
            u2 = c2v + 0.1f * (c2v + s2) * invn;
            float s = u0 + u1 + u2, sq = u0 * u0 + u1 * u1 + u2 * u2;
#pragma unroll
            for (int o = 32; o; o >>= 1) { s += __shfl_xor(s, o); sq += __shfl_xor(sq, o); }
            if (lane == 0) { red[wave] = s; red[4 + wave] = sq; }
        }
        __syncthreads();
        if (tid == 0) {
            red[0] = red[0] + red[1] + red[2] + red[3];
            red[4] = red[4] + red[5] + red[6] + red[7];
        }
        __syncthreads();
        if (tid < 256) {
            float mu   = red[0] / (float)D;
            float var  = red[4] / (float)D - mu * mu;
            float rstd = rsqrtf(var + EPS);
            float* outr = cd + (size_t)(c - 1) * D;
            outr[tid]       = (u0 - mu) * rstd * gamma[tid]       + beta[tid];
            outr[tid + 256] = (u1 - mu) * rstd * gamma[tid + 256] + beta[tid + 256];
            outr[tid + 512] = (u2 - mu) * rstd * gamma[tid + 512] + beta[tid + 512];
        }
    }
}

// ---------------- kC (512 thr): neg gram + ticket-gated final loss --------------
__global__ __launch_bounds__(512) void kC(const float* __restrict__ cd,
        const float* __restrict__ posp, unsigned int* __restrict__ negbits,
        unsigned int* __restrict__ tick, float* __restrict__ out) {
    int i = blockIdx.x;    // 0..94
    int tid = threadIdx.x, wave = tid >> 6, lane = tid & 63;
    __shared__ float rowi[D];
    __shared__ float red[8];
    __shared__ int winner;
    for (int t = tid; t < D; t += 512) rowi[t] = cd[(size_t)i * D + t];
    __syncthreads();
    float acc = 0.f;
    for (int j = wave; j < 95; j += 8) {
        const float* rj = cd + (size_t)j * D;
        float dot = 0.f;
#pragma unroll
        for (int t = 0; t < 12; ++t) dot += rowi[lane + 64 * t] * rj[lane + 64 * t];
#pragma unroll
        for (int o = 32; o; o >>= 1) dot += __shfl_xor(dot, o);
        if (lane == 0) acc += __expf(dot * (1.f / (float)D));
    }
    if (lane == 0) red[wave] = acc;
    __syncthreads();
    if (tid == 0) {
        float val = ((red[0] + red[1]) + (red[2] + red[3]))
                  + ((red[4] + red[5]) + (red[6] + red[7]));
        atomicExch(&negbits[i], __float_as_uint(val));   // device-scope publish
        __threadfence();
        winner = (atomicAdd(&tick[0], 1u) == 94u) ? 1 : 0; // 95th finisher wins
    }
    __syncthreads();
    if (winner && wave == 0) {
        __threadfence();                                 // acquire others' publishes
        double ng = (lane < 95)
            ? (double)__uint_as_float(atomicOr(&negbits[lane], 0u)) : 0.0;
        if (lane < 31)
            ng += (double)__uint_as_float(atomicOr(&negbits[64 + lane], 0u));
        double p = (double)posp[lane];
        if (lane < 32) p += (double)posp[64 + lane];
#pragma unroll
        for (int o = 32; o; o >>= 1) {
            ng += __shfl_xor(ng, o);
            p  += __shfl_xor(p, o);
        }
        if (lane == 0) out[0] = (float)(log(ng) - log(p));
    }
}

extern "C" void kernel_launch(void* const* d_in, const int* in_sizes, int n_in,
                              void* d_out, int out_size, void* d_ws, size_t ws_size,
                              hipStream_t stream) {
    const float* input_f  = (const float*)d_in[0];
    const float* char_dic = (const float*)d_in[1];
    const float* gamma    = (const float*)d_in[2];
    const float* beta     = (const float*)d_in[3];
    const int*   target   = (const int*)d_in[4];
    float* out = (float*)d_out;

    char* ws = (char*)d_ws;
    size_t off = 0;
    auto carve = [&](size_t bytes) -> void* {
        void* p = ws + off;
        off = (off + bytes + 255) & ~(size_t)255;
        return p;
    };
    // +192 pad rows: kB pad-row staging may read past class end (masked in epilogue)
    __hip_bfloat16* xgb = (__hip_bfloat16*)carve((size_t)(NROWS + 192) * D * 2);
    int*          perm    = (int*)  carve((size_t)M * 4);
    int*          counts  = (int*)  carve(NCLS * 4);
    int*          gofs    = (int*)  carve(NCLS * 4);
    float*        posp    = (float*)carve(NCLS * 4);
    float*        cd      = (float*)carve((size_t)95 * D * 4);
    unsigned int* negbits = (unsigned int*)carve(95 * 4);
    unsigned int* tick    = (unsigned int*)carve(64);

    (void)hipFuncSetAttribute((const void*)kB,
            hipFuncAttributeMaxDynamicSharedMemorySize, DYN_B);

    k2_lists<<<NCLS, 512, 0, stream>>>(target, char_dic, perm, counts, gofs, xgb, tick);
    k1_layernorm<<<M / 4, 256, 0, stream>>>(input_f, gamma, beta, perm, xgb);
    kB<<<NCLS + 95, 512, DYN_B, stream>>>(xgb, char_dic, gamma, beta, counts, gofs, posp, cd);
    kC<<<95, 512, 0, stream>>>(cd, posp, negbits, tick, out);
}